// Round 7
// baseline (457.613 us; speedup 1.0000x reference)
//
#include <hip/hip_runtime.h>
#include <hip/hip_bf16.h>

#define BB 8
#define SS 4096
#define DD 1024
#define KK 32
#define EE 8
#define PP 4

// ---- output float offsets (tuple concatenated flat, in return order) ----
#define O0 0L                    // expert_weights  (B,S,E)   262144
#define O1 262144L               // expert_indices  (B,S,E)   262144
#define O2 524288L               // phi_weights     (B,S,K)  1048576
#define O3 1572864L              // soft_slots      (B,K*D)   262144
#define O4 1835008L              // expert_inputs   (B,K*D)   262144
#define O5 2097152L              // phi_logits      (B,S,K)  1048576
#define O6 3145728L              // raw_gate_probs  (B,S,K)  1048576

// ---- workspace float offsets ----
#define WA 0L        // softmax partials: 128 blocks * 64 floats
#define WB 8192L     // final m / (1/sum) per (b,k): 8*64 floats
#define WC 16384L    // logits d-quarter partials (16.8MB) THEN k_slots partials

// ============ K1 v6: register-tiled logits GEMM ===========================
// Grid 256 = 64 token-tiles(512 tok) x 4 d-quarters(256 d). Block = 4 waves,
// wave = 128 tok x 32 k. Lane (i=lane>>2, j=lane&3): 8 tokens {t*16+i} x 8 k
// {j*8..j*8+8}; acc 64 VGPR. x streamed PER-LANE from global (never LDS);
// only W staged in LDS (8KB/chunk, double-buffered), read as 4-address
// multicast b128 (conflict-free). Per 4-d step: 256 FMA vs 8 LDS reads.
// Partial store: lane-contiguous [q][gwt][t][lane][8] (2KB/wave/t coalesced).
__global__ __launch_bounds__(256) void k_logits6(const float* __restrict__ x,
    const float* __restrict__ Wp, float* __restrict__ wsP)
{
    __shared__ float wl[2][64][32];
    const int tid  = threadIdx.x;
    const int wv   = __builtin_amdgcn_readfirstlane(tid >> 6);
    const int lane = tid & 63;
    const int i    = lane >> 2;
    const int j    = lane & 3;
    const int blk  = blockIdx.x;
    const int tile = blk >> 2, q = blk & 3;
    const int gwt  = tile * 4 + wv;          // global wave-tile id (128 tok)
    const long tok0 = (long)gwt * 128;
    const int d0 = q * 256;

    float4 a0[8], a1[8];
#pragma unroll
    for (int t = 0; t < 8; ++t) {
        a0[t] = make_float4(0.f, 0.f, 0.f, 0.f);
        a1[t] = make_float4(0.f, 0.f, 0.f, 0.f);
    }

    // per-lane x row pointers (8 token streams)
    const float* xr[8];
#pragma unroll
    for (int t = 0; t < 8; ++t)
        xr[t] = x + (tok0 + t * 16 + i) * DD + d0;

    // stage w chunk 0: 64 d x 32 k = 2048 floats, 8 per thread, coalesced
    {
        const float* wsrc = Wp + (long)d0 * KK;
        *reinterpret_cast<float4*>(&wl[0][0][0] + tid * 8) =
            *reinterpret_cast<const float4*>(wsrc + tid * 8);
        *reinterpret_cast<float4*>(&wl[0][0][0] + tid * 8 + 4) =
            *reinterpret_cast<const float4*>(wsrc + tid * 8 + 4);
    }
    __syncthreads();

    for (int c = 0; c < 4; ++c) {
        const int cur = c & 1;
        float4 wr0, wr1;
        if (c < 3) {                          // prefetch next w chunk early
            const float* wsrc = Wp + (long)(d0 + (c + 1) * 64) * KK;
            wr0 = *reinterpret_cast<const float4*>(wsrc + tid * 8);
            wr1 = *reinterpret_cast<const float4*>(wsrc + tid * 8 + 4);
        }
        const int db = c * 64;
#pragma unroll
        for (int dq = 0; dq < 16; ++dq) {
            float4 xv[8];
#pragma unroll
            for (int t = 0; t < 8; ++t)
                xv[t] = *reinterpret_cast<const float4*>(xr[t] + db + dq * 4);
#pragma unroll
            for (int dd = 0; dd < 4; ++dd) {
                const float4 w0 = *reinterpret_cast<const float4*>(&wl[cur][dq * 4 + dd][j * 8]);
                const float4 w1 = *reinterpret_cast<const float4*>(&wl[cur][dq * 4 + dd][j * 8 + 4]);
#pragma unroll
                for (int t = 0; t < 8; ++t) {
                    const float xs = (dd == 0) ? xv[t].x : (dd == 1) ? xv[t].y
                                   : (dd == 2) ? xv[t].z : xv[t].w;
                    a0[t].x = fmaf(xs, w0.x, a0[t].x);
                    a0[t].y = fmaf(xs, w0.y, a0[t].y);
                    a0[t].z = fmaf(xs, w0.z, a0[t].z);
                    a0[t].w = fmaf(xs, w0.w, a0[t].w);
                    a1[t].x = fmaf(xs, w1.x, a1[t].x);
                    a1[t].y = fmaf(xs, w1.y, a1[t].y);
                    a1[t].z = fmaf(xs, w1.z, a1[t].z);
                    a1[t].w = fmaf(xs, w1.w, a1[t].w);
                }
            }
        }
        __syncthreads();                      // all waves done reading wl[cur^1 prev]
        if (c < 3) {
            *reinterpret_cast<float4*>(&wl[cur ^ 1][0][0] + tid * 8)     = wr0;
            *reinterpret_cast<float4*>(&wl[cur ^ 1][0][0] + tid * 8 + 4) = wr1;
            __syncthreads();
        }
    }

    // partial store: [q][gwt][t][lane][8] -- lane-contiguous, 2KB/wave per t
    float* Pb = wsP + ((long)(q * 256 + gwt)) * 4096 + lane * 8;
#pragma unroll
    for (int t = 0; t < 8; ++t) {
        *reinterpret_cast<float4*>(Pb + t * 512)     = a0[t];
        *reinterpret_cast<float4*>(Pb + t * 512 + 4) = a1[t];
    }
}

// ============ K1b v3: combine 4 partials + bias + epilogue + sm stats ======
// 128 blocks x 256 thr; thread = one token. Gathers k_logits6's layout.
__global__ __launch_bounds__(256) void k_comb2(const float* __restrict__ wsP,
    const float* __restrict__ bp, float* __restrict__ out, float* __restrict__ ws)
{
    const int blk = blockIdx.x;            // = b*16 + sc (256-token chunk)
    const int tid = threadIdx.x;
    const int wv  = __builtin_amdgcn_readfirstlane(tid >> 6);
    const long g  = (long)blk * 256 + tid;
    const int gwt = (int)(g >> 7);
    const int r   = (int)(g & 127);
    const int tt  = r >> 4;
    const int ii  = r & 15;
    float acc[KK];
#pragma unroll
    for (int k = 0; k < KK; ++k) acc[k] = bp[k];
#pragma unroll
    for (int q = 0; q < 4; ++q) {
        const float* P = wsP + ((long)(q * 256 + gwt)) * 4096 + tt * 512 + ii * 32;
#pragma unroll
        for (int kq = 0; kq < 8; ++kq) {
            const float4 v = *reinterpret_cast<const float4*>(
                P + (kq >> 1) * 8 + (kq & 1) * 4);
            acc[kq * 4]     += v.x;
            acc[kq * 4 + 1] += v.y;
            acc[kq * 4 + 2] += v.z;
            acc[kq * 4 + 3] += v.w;
        }
    }
    float4* pl = reinterpret_cast<float4*>(out + O5 + g * KK);
#pragma unroll
    for (int j2 = 0; j2 < 8; ++j2)
        pl[j2] = make_float4(acc[4*j2], acc[4*j2+1], acc[4*j2+2], acc[4*j2+3]);
    float rg[KK];
#pragma unroll
    for (int e = 0; e < EE; ++e) {
        const float m = fmaxf(fmaxf(acc[4*e], acc[4*e+1]), fmaxf(acc[4*e+2], acc[4*e+3]));
        float s = 0.f;
#pragma unroll
        for (int p = 0; p < PP; ++p) { rg[4*e+p] = __expf(acc[4*e+p] - m); s += rg[4*e+p]; }
        const float ri = 1.f / s;
#pragma unroll
        for (int p = 0; p < PP; ++p) rg[4*e+p] *= ri;
    }
    float4* prg = reinterpret_cast<float4*>(out + O6 + g * KK);
#pragma unroll
    for (int j2 = 0; j2 < 8; ++j2)
        prg[j2] = make_float4(rg[4*j2], rg[4*j2+1], rg[4*j2+2], rg[4*j2+3]);
    float4* pew = reinterpret_cast<float4*>(out + O0 + g * EE);
    pew[0] = make_float4(0.125f, 0.125f, 0.125f, 0.125f);
    pew[1] = make_float4(0.125f, 0.125f, 0.125f, 0.125f);
    float4* pei = reinterpret_cast<float4*>(out + O1 + g * EE);
    pei[0] = make_float4(0.f, 1.f, 2.f, 3.f);
    pei[1] = make_float4(4.f, 5.f, 6.f, 7.f);

    // ---- seq-softmax partial stats over this 256-token chunk ----
    float m[KK];
#pragma unroll
    for (int k = 0; k < KK; ++k) m[k] = acc[k];
    for (int off = 1; off < 64; off <<= 1) {
#pragma unroll
        for (int k = 0; k < KK; ++k) m[k] = fmaxf(m[k], __shfl_xor(m[k], off));
    }
    __shared__ float lm[4][KK];
    __shared__ float lsum[4][KK];
    if ((tid & 63) == 0) {
#pragma unroll
        for (int k = 0; k < KK; ++k) lm[wv][k] = m[k];
    }
    __syncthreads();
#pragma unroll
    for (int k = 0; k < KK; ++k)
        m[k] = fmaxf(fmaxf(lm[0][k], lm[1][k]), fmaxf(lm[2][k], lm[3][k]));
    float sv[KK];
#pragma unroll
    for (int k = 0; k < KK; ++k) sv[k] = __expf(acc[k] - m[k]);
    for (int off = 1; off < 64; off <<= 1) {
#pragma unroll
        for (int k = 0; k < KK; ++k) sv[k] += __shfl_xor(sv[k], off);
    }
    if ((tid & 63) == 0) {
#pragma unroll
        for (int k = 0; k < KK; ++k) lsum[wv][k] = sv[k];
    }
    __syncthreads();
    if (tid == 0) {
#pragma unroll
        for (int k = 0; k < KK; ++k) {
            ws[WA + (long)blk * 64 + k]      = m[k];
            ws[WA + (long)blk * 64 + 32 + k] = lsum[0][k] + lsum[1][k] + lsum[2][k] + lsum[3][k];
        }
    }
}

// ============ K1 fallback (direct) + stats kernel, if ws is tiny ===========
__global__ __launch_bounds__(256) void k_logits4(const float* __restrict__ x,
    const float* __restrict__ Wp, const float* __restrict__ bp,
    float* __restrict__ out)
{
    __shared__ float xl[2][64][68];
    __shared__ float wl[2][64][32];
    const int tid  = threadIdx.x;
    const int wv   = __builtin_amdgcn_readfirstlane(tid >> 6);
    const int lane = tid & 63;
    const long tok0 = (long)blockIdx.x * 64;
    const long g   = tok0 + lane;
    const int sr = tid >> 2;
    const int sco = (tid & 3) * 4;
    float acc[8];
#pragma unroll
    for (int j = 0; j < 8; ++j) acc[j] = 0.f;
    float4 xr[4], wr[2];
#pragma unroll
    for (int j = 0; j < 4; ++j)
        xr[j] = *reinterpret_cast<const float4*>(x + (tok0 + sr) * DD + sco + j * 16);
#pragma unroll
    for (int j = 0; j < 2; ++j)
        wr[j] = *reinterpret_cast<const float4*>(Wp + tid * 8 + j * 4);
#pragma unroll
    for (int j = 0; j < 4; ++j)
        *reinterpret_cast<float4*>(&xl[0][sr][sco + j * 16]) = xr[j];
#pragma unroll
    for (int j = 0; j < 2; ++j)
        *reinterpret_cast<float4*>(&wl[0][0][0] + tid * 8 + j * 4) = wr[j];
    __syncthreads();
    for (int c = 0; c < 16; ++c) {
        const int cb = c & 1;
        if (c < 15) {
            const long dg = (long)(c + 1) * 64;
#pragma unroll
            for (int j = 0; j < 4; ++j)
                xr[j] = *reinterpret_cast<const float4*>(
                    x + (tok0 + sr) * DD + dg + sco + j * 16);
#pragma unroll
            for (int j = 0; j < 2; ++j)
                wr[j] = *reinterpret_cast<const float4*>(Wp + dg * KK + tid * 8 + j * 4);
        }
        const float* xb = &xl[cb][lane][0];
        const float* wb = &wl[cb][0][0] + wv * 8;
#pragma unroll 4
        for (int dq = 0; dq < 16; ++dq) {
            const float4 xv = *reinterpret_cast<const float4*>(xb + dq * 4);
#pragma unroll
            for (int dd = 0; dd < 4; ++dd) {
                const float xs = (dd == 0) ? xv.x : (dd == 1) ? xv.y
                               : (dd == 2) ? xv.z : xv.w;
                const float4 w0 = *reinterpret_cast<const float4*>(wb + (dq * 4 + dd) * 32);
                const float4 w1 = *reinterpret_cast<const float4*>(wb + (dq * 4 + dd) * 32 + 4);
                acc[0] = fmaf(xs, w0.x, acc[0]);
                acc[1] = fmaf(xs, w0.y, acc[1]);
                acc[2] = fmaf(xs, w0.z, acc[2]);
                acc[3] = fmaf(xs, w0.w, acc[3]);
                acc[4] = fmaf(xs, w1.x, acc[4]);
                acc[5] = fmaf(xs, w1.y, acc[5]);
                acc[6] = fmaf(xs, w1.z, acc[6]);
                acc[7] = fmaf(xs, w1.w, acc[7]);
            }
        }
        if (c < 15) {
#pragma unroll
            for (int j = 0; j < 4; ++j)
                *reinterpret_cast<float4*>(&xl[cb ^ 1][sr][sco + j * 16]) = xr[j];
#pragma unroll
            for (int j = 0; j < 2; ++j)
                *reinterpret_cast<float4*>(&wl[cb ^ 1][0][0] + tid * 8 + j * 4) = wr[j];
        }
        __syncthreads();
    }
#pragma unroll
    for (int j = 0; j < 8; ++j) acc[j] += bp[wv * 8 + j];
    float* o5 = out + O5 + g * KK + wv * 8;
    *reinterpret_cast<float4*>(o5)     = make_float4(acc[0], acc[1], acc[2], acc[3]);
    *reinterpret_cast<float4*>(o5 + 4) = make_float4(acc[4], acc[5], acc[6], acc[7]);
    float rg[8];
#pragma unroll
    for (int e = 0; e < 2; ++e) {
        const float* a = &acc[e * 4];
        const float m = fmaxf(fmaxf(a[0], a[1]), fmaxf(a[2], a[3]));
        float s = 0.f;
#pragma unroll
        for (int p = 0; p < PP; ++p) { rg[e*4+p] = __expf(a[p] - m); s += rg[e*4+p]; }
        const float ri = 1.f / s;
#pragma unroll
        for (int p = 0; p < PP; ++p) rg[e*4+p] *= ri;
    }
    float* o6 = out + O6 + g * KK + wv * 8;
    *reinterpret_cast<float4*>(o6)     = make_float4(rg[0], rg[1], rg[2], rg[3]);
    *reinterpret_cast<float4*>(o6 + 4) = make_float4(rg[4], rg[5], rg[6], rg[7]);
    if (wv == 0) {
        float4* p = reinterpret_cast<float4*>(out + O0 + g * EE);
        p[0] = make_float4(0.125f, 0.125f, 0.125f, 0.125f);
        p[1] = make_float4(0.125f, 0.125f, 0.125f, 0.125f);
    } else if (wv == 1) {
        float4* p = reinterpret_cast<float4*>(out + O1 + g * EE);
        p[0] = make_float4(0.f, 1.f, 2.f, 3.f);
        p[1] = make_float4(4.f, 5.f, 6.f, 7.f);
    }
}

__global__ __launch_bounds__(256) void k_smpart(const float* __restrict__ out,
                                                float* __restrict__ ws)
{
    const int blk = blockIdx.x;
    const int tid = threadIdx.x;
    const int wv  = __builtin_amdgcn_readfirstlane(tid >> 6);
    const int b = blk >> 4, sc = blk & 15;
    const long s  = (long)sc * 256 + tid;
    const float* row = out + O5 + ((long)b * SS + s) * KK;
    float v[KK];
    const float4* r4 = reinterpret_cast<const float4*>(row);
#pragma unroll
    for (int q = 0; q < 8; ++q) {
        const float4 t = r4[q];
        v[4*q] = t.x; v[4*q+1] = t.y; v[4*q+2] = t.z; v[4*q+3] = t.w;
    }
    float m[KK];
#pragma unroll
    for (int k = 0; k < KK; ++k) m[k] = v[k];
    for (int off = 1; off < 64; off <<= 1) {
#pragma unroll
        for (int k = 0; k < KK; ++k) m[k] = fmaxf(m[k], __shfl_xor(m[k], off));
    }
    __shared__ float lm[4][KK];
    __shared__ float lsum[4][KK];
    if ((tid & 63) == 0) {
#pragma unroll
        for (int k = 0; k < KK; ++k) lm[wv][k] = m[k];
    }
    __syncthreads();
#pragma unroll
    for (int k = 0; k < KK; ++k)
        m[k] = fmaxf(fmaxf(lm[0][k], lm[1][k]), fmaxf(lm[2][k], lm[3][k]));
    float sv[KK];
#pragma unroll
    for (int k = 0; k < KK; ++k) sv[k] = __expf(v[k] - m[k]);
    for (int off = 1; off < 64; off <<= 1) {
#pragma unroll
        for (int k = 0; k < KK; ++k) sv[k] += __shfl_xor(sv[k], off);
    }
    if ((tid & 63) == 0) {
#pragma unroll
        for (int k = 0; k < KK; ++k) lsum[wv][k] = sv[k];
    }
    __syncthreads();
    if (tid == 0) {
#pragma unroll
        for (int k = 0; k < KK; ++k) {
            ws[WA + (long)blk * 64 + k]      = m[k];
            ws[WA + (long)blk * 64 + 32 + k] = lsum[0][k] + lsum[1][k] + lsum[2][k] + lsum[3][k];
        }
    }
}

// ============ K2b: combine 16 chunk stats -> final m, 1/sum per (b,k) ======
__global__ __launch_bounds__(256) void k_smcomb(float* __restrict__ ws)
{
    const int tid = threadIdx.x;           // = b*32 + k
    const int b = tid >> 5, k = tid & 31;
    float m = -1e30f, s = 0.f;
    for (int c = 0; c < 16; ++c) {
        const float mc = ws[WA + (long)(b * 16 + c) * 64 + k];
        const float sc = ws[WA + (long)(b * 16 + c) * 64 + 32 + k];
        const float nm = fmaxf(m, mc);
        s = s * __expf(m - nm) + sc * __expf(mc - nm);
        m = nm;
    }
    ws[WB + (long)b * 64 + k]      = m;
    ws[WB + (long)b * 64 + 32 + k] = 1.f / s;
}

// ============ K2c: phi_weights = exp(logit - m) * rinv ====================
__global__ __launch_bounds__(256) void k_pw(float* __restrict__ out,
                                            const float* __restrict__ ws)
{
    const long i4 = (long)blockIdx.x * 256 + threadIdx.x;   // < 262144
    const float4 l4 = reinterpret_cast<const float4*>(out + O5)[i4];
    const long idx = i4 * 4;
    const int b  = (int)(idx >> 17);
    const int k0 = (int)(idx & 31);
    const float* mb = ws + WB + (long)b * 64;
    const float lv[4] = {l4.x, l4.y, l4.z, l4.w};
    float r[4];
#pragma unroll
    for (int j = 0; j < 4; ++j) {
        const int k = k0 + j;
        r[j] = __expf(lv[j] - mb[k]) * mb[32 + k];
    }
    reinterpret_cast<float4*>(out + O2)[i4] = make_float4(r[0], r[1], r[2], r[3]);
}

// ============ K3 v2: soft_slots partials, pw staged in LDS ================
__global__ __launch_bounds__(256) void k_slots2(const float* __restrict__ x,
    const float* __restrict__ out, float* __restrict__ dst, int SC, int SLEN)
{
    __shared__ float pwl[2][64 * KK];
    const int tid = threadIdx.x;
    const int blk = blockIdx.x;
    const int sc  = blk % SC;
    const int t2  = blk / SC;
    const int dc  = t2 & 3;
    const int b   = t2 >> 2;
    const int d   = dc * 256 + tid;
    float acc[KK];
#pragma unroll
    for (int k = 0; k < KK; ++k) acc[k] = 0.f;
    const long s0 = (long)sc * SLEN;
    const float* pw = out + O2 + ((long)b * SS + s0) * KK;
    const float* xp = x + ((long)b * SS + s0) * DD + d;
    const int NCH = SLEN >> 6;

    float4 r0 = *reinterpret_cast<const float4*>(pw + tid * 8);
    float4 r1 = *reinterpret_cast<const float4*>(pw + tid * 8 + 4);
    *reinterpret_cast<float4*>(&pwl[0][tid * 8])     = r0;
    *reinterpret_cast<float4*>(&pwl[0][tid * 8 + 4]) = r1;
    __syncthreads();

    for (int ch = 0; ch < NCH; ++ch) {
        const int cb = ch & 1;
        if (ch + 1 < NCH) {
            const float* pn = pw + (long)(ch + 1) * 64 * KK;
            r0 = *reinterpret_cast<const float4*>(pn + tid * 8);
            r1 = *reinterpret_cast<const float4*>(pn + tid * 8 + 4);
        }
        const float* xc = xp + (long)ch * 64 * DD;
        const float* pb = &pwl[cb][0];
#pragma unroll 8
        for (int i = 0; i < 64; ++i) {
            const float xv = xc[(long)i * DD];
#pragma unroll
            for (int q = 0; q < 8; ++q) {
                const float4 w = *reinterpret_cast<const float4*>(pb + i * KK + q * 4);
                acc[4*q]   = fmaf(w.x, xv, acc[4*q]);
                acc[4*q+1] = fmaf(w.y, xv, acc[4*q+1]);
                acc[4*q+2] = fmaf(w.z, xv, acc[4*q+2]);
                acc[4*q+3] = fmaf(w.w, xv, acc[4*q+3]);
            }
        }
        if (ch + 1 < NCH) {
            *reinterpret_cast<float4*>(&pwl[cb ^ 1][tid * 8])     = r0;
            *reinterpret_cast<float4*>(&pwl[cb ^ 1][tid * 8 + 4]) = r1;
        }
        __syncthreads();
    }
    float* o = dst + ((long)(sc * BB + b) * KK) * DD + d;
#pragma unroll
    for (int k = 0; k < KK; ++k) o[(long)k * DD] = acc[k];
}

// ============ K4: reduce SC partials -> soft_slots + expert_inputs =========
__global__ __launch_bounds__(256) void k_red(const float* __restrict__ src,
                                             float* __restrict__ out, int SC)
{
    const long i4 = (long)blockIdx.x * 256 + threadIdx.x;   // < 65536
    float4 s = make_float4(0.f, 0.f, 0.f, 0.f);
    const float4* p = reinterpret_cast<const float4*>(src);
    for (int c = 0; c < SC; ++c) {
        const float4 t = p[(long)c * 65536 + i4];
        s.x += t.x; s.y += t.y; s.z += t.z; s.w += t.w;
    }
    reinterpret_cast<float4*>(out + O3)[i4] = s;
    reinterpret_cast<float4*>(out + O4)[i4] = s;
}

extern "C" void kernel_launch(void* const* d_in, const int* in_sizes, int n_in,
                              void* d_out, int out_size, void* d_ws, size_t ws_size,
                              hipStream_t stream)
{
    const float* x  = (const float*)d_in[0];
    const float* Wp = (const float*)d_in[1];
    const float* bp = (const float*)d_in[2];
    float* out = (float*)d_out;
    float* ws  = (float*)d_ws;

    const size_t wfloats = ws_size / 4;
    const long wsP_floats = 4L * 256 * 4096;   // 4.19M floats = 16.8 MB

    // ---- logits ----
    if (wfloats >= (size_t)(WC + wsP_floats)) {
        hipLaunchKernelGGL(k_logits6, dim3(256), dim3(256), 0, stream, x, Wp, ws + WC);
        hipLaunchKernelGGL(k_comb2,   dim3(128), dim3(256), 0, stream, ws + WC, bp, out, ws);
    } else {
        hipLaunchKernelGGL(k_logits4, dim3(512), dim3(256), 0, stream, x, Wp, bp, out);
        hipLaunchKernelGGL(k_smpart,  dim3(128), dim3(256), 0, stream, out, ws);
    }

    hipLaunchKernelGGL(k_smcomb, dim3(1),    dim3(256), 0, stream, ws);
    hipLaunchKernelGGL(k_pw,     dim3(1024), dim3(256), 0, stream, out, ws);

    // ---- soft slots (WC region reused after k_comb2 consumed wsP) ----
    int SC = 0;
    if      (wfloats >= (size_t)(WC + 32L * 262144)) SC = 32;
    else if (wfloats >= (size_t)(WC + 16L * 262144)) SC = 16;
    else if (wfloats >= (size_t)(WC +  8L * 262144)) SC = 8;
    else if (wfloats >= (size_t)(WC +  4L * 262144)) SC = 4;
    else if (wfloats >= (size_t)(WC +  2L * 262144)) SC = 2;
    else if (wfloats >= (size_t)(WC +  1L * 262144)) SC = 1;

    if (SC >= 1) {
        hipLaunchKernelGGL(k_slots2, dim3(BB * 4 * SC), dim3(256), 0, stream,
                           x, out, ws + WC, SC, SS / SC);
        hipLaunchKernelGGL(k_red,    dim3(256), dim3(256), 0, stream, ws + WC, out, SC);
    } else {
        hipLaunchKernelGGL(k_slots2, dim3(BB * 4), dim3(256), 0, stream,
                           x, out, out + O3, 1, SS);
        hipLaunchKernelGGL(k_red,    dim3(256), dim3(256), 0, stream, out + O3, out, 1);
    }
}

// Round 8
// 193.989 us; speedup vs baseline: 2.3590x; 2.3590x over previous
//
#include <hip/hip_runtime.h>
#include <hip/hip_bf16.h>

#define BB 8
#define SS 4096
#define DD 1024
#define KK 32
#define EE 8
#define PP 4

// ---- output float offsets (tuple concatenated flat, in return order) ----
#define O0 0L                    // expert_weights  (B,S,E)   262144
#define O1 262144L               // expert_indices  (B,S,E)   262144
#define O2 524288L               // phi_weights     (B,S,K)  1048576
#define O3 1572864L              // soft_slots      (B,K*D)   262144
#define O4 1835008L              // expert_inputs   (B,K*D)   262144
#define O5 2097152L              // phi_logits      (B,S,K)  1048576
#define O6 3145728L              // raw_gate_probs  (B,S,K)  1048576

// ---- workspace float offsets ----
#define WA 0L        // softmax partials: 128 blocks * 64 floats
#define WB 8192L     // final m / (1/sum) per (b,k): 8*64 floats
#define WC 16384L    // logits d-quarter partials (16.8MB) THEN k_slots partials

// ============ K1 v8: register-tiled logits GEMM, both operands via LDS =====
// Grid 256 = 64 token-tiles(512 tok) x 4 d-quarters(256 d). Block = 4 waves;
// wave = 128 tok x 32 k; lane (i=lane>>2, j=lane&3) = 8 tok {r*16+i} x 8 k
// {8j..8j+8}; acc 64 scalars. Per 4-d step: 256 FMA-instr vs 8 x-b128 (per-
// lane distinct rows, <=2-way bank) + 8 w-b128 (16-way broadcast, free).
// x tile [512 tok][16 d] staged coalesced (64B/row); W chunk transposed to
// dq-interleaved layout so each lane w-quad is one aligned b128.
__global__ __launch_bounds__(256) void k_logits8(const float* __restrict__ x,
    const float* __restrict__ Wp, float* __restrict__ wsP)
{
    __shared__ float xl[512][20];      // 40KB, stride 20: 16B-aligned rows
    __shared__ float wT[4 * 144];      // [dq][j*36 + m*4 + dd], 2.3KB
    const int tid  = threadIdx.x;
    const int wv   = __builtin_amdgcn_readfirstlane(tid >> 6);
    const int lane = tid & 63;
    const int i    = lane >> 2;
    const int j    = lane & 3;
    const int blk  = blockIdx.x;
    const int tile = blk >> 2, q = blk & 3;
    const long tok0 = (long)tile * 512;
    const int d0 = q * 256;

    float a[8][8];
#pragma unroll
    for (int r = 0; r < 8; ++r)
#pragma unroll
        for (int m = 0; m < 8; ++m) a[r][m] = 0.f;

    // w-stage decomposition for this thread (2 consecutive floats)
    const int wf   = tid * 2;
    const int wd   = wf >> 5;          // d_loc 0..15
    const int wk   = wf & 31;          // k (even)
    const int wslot = (wd >> 2) * 144 + (wk >> 3) * 36 + (wk & 7) * 4 + (wd & 3);
    const int wslot2 = (wd >> 2) * 144 + ((wk+1) >> 3) * 36 + ((wk+1) & 7) * 4 + (wd & 3);

    float4 xpf[8];
    float2 wpf;
    // ---- prefetch chunk 0 ----
#pragma unroll
    for (int p = 0; p < 4; ++p)
        xpf[p] = *reinterpret_cast<const float4*>(x + (tok0 + tid) * DD + d0 + p * 4);
#pragma unroll
    for (int p = 0; p < 4; ++p)
        xpf[4 + p] = *reinterpret_cast<const float4*>(x + (tok0 + 256 + tid) * DD + d0 + p * 4);
    wpf = *reinterpret_cast<const float2*>(Wp + (long)(d0 + wd) * KK + wk);

    for (int c = 0; c < 16; ++c) {
        // ---- write staged regs to LDS ----
#pragma unroll
        for (int p = 0; p < 4; ++p)
            *reinterpret_cast<float4*>(&xl[tid][p * 4]) = xpf[p];
#pragma unroll
        for (int p = 0; p < 4; ++p)
            *reinterpret_cast<float4*>(&xl[256 + tid][p * 4]) = xpf[4 + p];
        wT[wslot]  = wpf.x;
        wT[wslot2] = wpf.y;
        __syncthreads();
        // ---- prefetch next chunk (global latency hidden under compute) ----
        if (c < 15) {
            const long db = (long)d0 + (c + 1) * 16;
#pragma unroll
            for (int p = 0; p < 4; ++p)
                xpf[p] = *reinterpret_cast<const float4*>(x + (tok0 + tid) * DD + db + p * 4);
#pragma unroll
            for (int p = 0; p < 4; ++p)
                xpf[4 + p] = *reinterpret_cast<const float4*>(x + (tok0 + 256 + tid) * DD + db + p * 4);
            wpf = *reinterpret_cast<const float2*>(Wp + (db + wd) * KK + wk);
        }
        // ---- compute 16 d (4 dq steps) ----
#pragma unroll
        for (int dq = 0; dq < 4; ++dq) {
            float4 xv[8];
#pragma unroll
            for (int r = 0; r < 8; ++r)
                xv[r] = *reinterpret_cast<const float4*>(&xl[wv * 128 + r * 16 + i][dq * 4]);
            float4 wq[8];
#pragma unroll
            for (int m = 0; m < 8; ++m)
                wq[m] = *reinterpret_cast<const float4*>(&wT[dq * 144 + j * 36 + m * 4]);
#pragma unroll
            for (int r = 0; r < 8; ++r)
#pragma unroll
                for (int m = 0; m < 8; ++m) {
                    a[r][m] = fmaf(xv[r].x, wq[m].x, a[r][m]);
                    a[r][m] = fmaf(xv[r].y, wq[m].y, a[r][m]);
                    a[r][m] = fmaf(xv[r].z, wq[m].z, a[r][m]);
                    a[r][m] = fmaf(xv[r].w, wq[m].w, a[r][m]);
                }
        }
        __syncthreads();
    }

    // ---- partial store: wsP[q][token][32k], 2KB contiguous per wave-row ----
#pragma unroll
    for (int r = 0; r < 8; ++r) {
        const long t = tok0 + wv * 128 + r * 16 + i;
        float* o = wsP + ((long)q * 32768 + t) * KK + j * 8;
        *reinterpret_cast<float4*>(o)     = make_float4(a[r][0], a[r][1], a[r][2], a[r][3]);
        *reinterpret_cast<float4*>(o + 4) = make_float4(a[r][4], a[r][5], a[r][6], a[r][7]);
    }
}

// ============ K1b: combine 4 d-quarter partials + bias + epilogue + stats ==
__global__ __launch_bounds__(256) void k_comb2(const float* __restrict__ wsP,
    const float* __restrict__ bp, float* __restrict__ out, float* __restrict__ ws)
{
    const int blk = blockIdx.x;            // = b*16 + sc (256-token chunk)
    const int tid = threadIdx.x;
    const int wv  = __builtin_amdgcn_readfirstlane(tid >> 6);
    const long g  = (long)blk * 256 + tid;
    float acc[KK];
#pragma unroll
    for (int k = 0; k < KK; ++k) acc[k] = bp[k];
#pragma unroll
    for (int q = 0; q < 4; ++q) {
        const float4* p = reinterpret_cast<const float4*>(wsP + ((long)q * 32768 + g) * KK);
#pragma unroll
        for (int m = 0; m < 8; ++m) {
            const float4 v = p[m];
            acc[4*m]   += v.x;
            acc[4*m+1] += v.y;
            acc[4*m+2] += v.z;
            acc[4*m+3] += v.w;
        }
    }
    float4* pl = reinterpret_cast<float4*>(out + O5 + g * KK);
#pragma unroll
    for (int m = 0; m < 8; ++m)
        pl[m] = make_float4(acc[4*m], acc[4*m+1], acc[4*m+2], acc[4*m+3]);
    float rg[KK];
#pragma unroll
    for (int e = 0; e < EE; ++e) {
        const float mx = fmaxf(fmaxf(acc[4*e], acc[4*e+1]), fmaxf(acc[4*e+2], acc[4*e+3]));
        float s = 0.f;
#pragma unroll
        for (int p = 0; p < PP; ++p) { rg[4*e+p] = __expf(acc[4*e+p] - mx); s += rg[4*e+p]; }
        const float ri = 1.f / s;
#pragma unroll
        for (int p = 0; p < PP; ++p) rg[4*e+p] *= ri;
    }
    float4* prg = reinterpret_cast<float4*>(out + O6 + g * KK);
#pragma unroll
    for (int m = 0; m < 8; ++m)
        prg[m] = make_float4(rg[4*m], rg[4*m+1], rg[4*m+2], rg[4*m+3]);
    float4* pew = reinterpret_cast<float4*>(out + O0 + g * EE);
    pew[0] = make_float4(0.125f, 0.125f, 0.125f, 0.125f);
    pew[1] = make_float4(0.125f, 0.125f, 0.125f, 0.125f);
    float4* pei = reinterpret_cast<float4*>(out + O1 + g * EE);
    pei[0] = make_float4(0.f, 1.f, 2.f, 3.f);
    pei[1] = make_float4(4.f, 5.f, 6.f, 7.f);

    // ---- seq-softmax partial stats over this 256-token chunk ----
    float m[KK];
#pragma unroll
    for (int k = 0; k < KK; ++k) m[k] = acc[k];
    for (int off = 1; off < 64; off <<= 1) {
#pragma unroll
        for (int k = 0; k < KK; ++k) m[k] = fmaxf(m[k], __shfl_xor(m[k], off));
    }
    __shared__ float lm[4][KK];
    __shared__ float lsum[4][KK];
    if ((tid & 63) == 0) {
#pragma unroll
        for (int k = 0; k < KK; ++k) lm[wv][k] = m[k];
    }
    __syncthreads();
#pragma unroll
    for (int k = 0; k < KK; ++k)
        m[k] = fmaxf(fmaxf(lm[0][k], lm[1][k]), fmaxf(lm[2][k], lm[3][k]));
    float sv[KK];
#pragma unroll
    for (int k = 0; k < KK; ++k) sv[k] = __expf(acc[k] - m[k]);
    for (int off = 1; off < 64; off <<= 1) {
#pragma unroll
        for (int k = 0; k < KK; ++k) sv[k] += __shfl_xor(sv[k], off);
    }
    if ((tid & 63) == 0) {
#pragma unroll
        for (int k = 0; k < KK; ++k) lsum[wv][k] = sv[k];
    }
    __syncthreads();
    if (tid == 0) {
#pragma unroll
        for (int k = 0; k < KK; ++k) {
            ws[WA + (long)blk * 64 + k]      = m[k];
            ws[WA + (long)blk * 64 + 32 + k] = lsum[0][k] + lsum[1][k] + lsum[2][k] + lsum[3][k];
        }
    }
}

// ============ K1 fallback (v4 direct) + stats kernel, if ws is tiny ========
__global__ __launch_bounds__(256) void k_logits4(const float* __restrict__ x,
    const float* __restrict__ Wp, const float* __restrict__ bp,
    float* __restrict__ out)
{
    __shared__ float xl[2][64][68];
    __shared__ float wl[2][64][32];
    const int tid  = threadIdx.x;
    const int wv   = __builtin_amdgcn_readfirstlane(tid >> 6);
    const int lane = tid & 63;
    const long tok0 = (long)blockIdx.x * 64;
    const long g   = tok0 + lane;
    const int sr = tid >> 2;
    const int sco = (tid & 3) * 4;
    float acc[8];
#pragma unroll
    for (int j = 0; j < 8; ++j) acc[j] = 0.f;
    float4 xr[4], wr[2];
#pragma unroll
    for (int j = 0; j < 4; ++j)
        xr[j] = *reinterpret_cast<const float4*>(x + (tok0 + sr) * DD + sco + j * 16);
#pragma unroll
    for (int j = 0; j < 2; ++j)
        wr[j] = *reinterpret_cast<const float4*>(Wp + tid * 8 + j * 4);
#pragma unroll
    for (int j = 0; j < 4; ++j)
        *reinterpret_cast<float4*>(&xl[0][sr][sco + j * 16]) = xr[j];
#pragma unroll
    for (int j = 0; j < 2; ++j)
        *reinterpret_cast<float4*>(&wl[0][0][0] + tid * 8 + j * 4) = wr[j];
    __syncthreads();
    for (int c = 0; c < 16; ++c) {
        const int cb = c & 1;
        if (c < 15) {
            const long dg = (long)(c + 1) * 64;
#pragma unroll
            for (int j = 0; j < 4; ++j)
                xr[j] = *reinterpret_cast<const float4*>(
                    x + (tok0 + sr) * DD + dg + sco + j * 16);
#pragma unroll
            for (int j = 0; j < 2; ++j)
                wr[j] = *reinterpret_cast<const float4*>(Wp + dg * KK + tid * 8 + j * 4);
        }
        const float* xb = &xl[cb][lane][0];
        const float* wb = &wl[cb][0][0] + wv * 8;
#pragma unroll 4
        for (int dq = 0; dq < 16; ++dq) {
            const float4 xv = *reinterpret_cast<const float4*>(xb + dq * 4);
#pragma unroll
            for (int dd = 0; dd < 4; ++dd) {
                const float xs = (dd == 0) ? xv.x : (dd == 1) ? xv.y
                               : (dd == 2) ? xv.z : xv.w;
                const float4 w0 = *reinterpret_cast<const float4*>(wb + (dq * 4 + dd) * 32);
                const float4 w1 = *reinterpret_cast<const float4*>(wb + (dq * 4 + dd) * 32 + 4);
                acc[0] = fmaf(xs, w0.x, acc[0]);
                acc[1] = fmaf(xs, w0.y, acc[1]);
                acc[2] = fmaf(xs, w0.z, acc[2]);
                acc[3] = fmaf(xs, w0.w, acc[3]);
                acc[4] = fmaf(xs, w1.x, acc[4]);
                acc[5] = fmaf(xs, w1.y, acc[5]);
                acc[6] = fmaf(xs, w1.z, acc[6]);
                acc[7] = fmaf(xs, w1.w, acc[7]);
            }
        }
        if (c < 15) {
#pragma unroll
            for (int j = 0; j < 4; ++j)
                *reinterpret_cast<float4*>(&xl[cb ^ 1][sr][sco + j * 16]) = xr[j];
#pragma unroll
            for (int j = 0; j < 2; ++j)
                *reinterpret_cast<float4*>(&wl[cb ^ 1][0][0] + tid * 8 + j * 4) = wr[j];
        }
        __syncthreads();
    }
#pragma unroll
    for (int j = 0; j < 8; ++j) acc[j] += bp[wv * 8 + j];
    float* o5 = out + O5 + g * KK + wv * 8;
    *reinterpret_cast<float4*>(o5)     = make_float4(acc[0], acc[1], acc[2], acc[3]);
    *reinterpret_cast<float4*>(o5 + 4) = make_float4(acc[4], acc[5], acc[6], acc[7]);
    float rg[8];
#pragma unroll
    for (int e = 0; e < 2; ++e) {
        const float* aa = &acc[e * 4];
        const float m = fmaxf(fmaxf(aa[0], aa[1]), fmaxf(aa[2], aa[3]));
        float s = 0.f;
#pragma unroll
        for (int p = 0; p < PP; ++p) { rg[e*4+p] = __expf(aa[p] - m); s += rg[e*4+p]; }
        const float ri = 1.f / s;
#pragma unroll
        for (int p = 0; p < PP; ++p) rg[e*4+p] *= ri;
    }
    float* o6 = out + O6 + g * KK + wv * 8;
    *reinterpret_cast<float4*>(o6)     = make_float4(rg[0], rg[1], rg[2], rg[3]);
    *reinterpret_cast<float4*>(o6 + 4) = make_float4(rg[4], rg[5], rg[6], rg[7]);
    if (wv == 0) {
        float4* p = reinterpret_cast<float4*>(out + O0 + g * EE);
        p[0] = make_float4(0.125f, 0.125f, 0.125f, 0.125f);
        p[1] = make_float4(0.125f, 0.125f, 0.125f, 0.125f);
    } else if (wv == 1) {
        float4* p = reinterpret_cast<float4*>(out + O1 + g * EE);
        p[0] = make_float4(0.f, 1.f, 2.f, 3.f);
        p[1] = make_float4(4.f, 5.f, 6.f, 7.f);
    }
}

__global__ __launch_bounds__(256) void k_smpart(const float* __restrict__ out,
                                                float* __restrict__ ws)
{
    const int blk = blockIdx.x;
    const int tid = threadIdx.x;
    const int wv  = __builtin_amdgcn_readfirstlane(tid >> 6);
    const int b = blk >> 4, sc = blk & 15;
    const long s  = (long)sc * 256 + tid;
    const float* row = out + O5 + ((long)b * SS + s) * KK;
    float v[KK];
    const float4* r4 = reinterpret_cast<const float4*>(row);
#pragma unroll
    for (int q = 0; q < 8; ++q) {
        const float4 t = r4[q];
        v[4*q] = t.x; v[4*q+1] = t.y; v[4*q+2] = t.z; v[4*q+3] = t.w;
    }
    float m[KK];
#pragma unroll
    for (int k = 0; k < KK; ++k) m[k] = v[k];
    for (int off = 1; off < 64; off <<= 1) {
#pragma unroll
        for (int k = 0; k < KK; ++k) m[k] = fmaxf(m[k], __shfl_xor(m[k], off));
    }
    __shared__ float lm[4][KK];
    __shared__ float lsum[4][KK];
    if ((tid & 63) == 0) {
#pragma unroll
        for (int k = 0; k < KK; ++k) lm[wv][k] = m[k];
    }
    __syncthreads();
#pragma unroll
    for (int k = 0; k < KK; ++k)
        m[k] = fmaxf(fmaxf(lm[0][k], lm[1][k]), fmaxf(lm[2][k], lm[3][k]));
    float sv[KK];
#pragma unroll
    for (int k = 0; k < KK; ++k) sv[k] = __expf(v[k] - m[k]);
    for (int off = 1; off < 64; off <<= 1) {
#pragma unroll
        for (int k = 0; k < KK; ++k) sv[k] += __shfl_xor(sv[k], off);
    }
    if ((tid & 63) == 0) {
#pragma unroll
        for (int k = 0; k < KK; ++k) lsum[wv][k] = sv[k];
    }
    __syncthreads();
    if (tid == 0) {
#pragma unroll
        for (int k = 0; k < KK; ++k) {
            ws[WA + (long)blk * 64 + k]      = m[k];
            ws[WA + (long)blk * 64 + 32 + k] = lsum[0][k] + lsum[1][k] + lsum[2][k] + lsum[3][k];
        }
    }
}

// ============ K2b: combine 16 chunk stats -> final m, 1/sum per (b,k) ======
__global__ __launch_bounds__(256) void k_smcomb(float* __restrict__ ws)
{
    const int tid = threadIdx.x;           // = b*32 + k
    const int b = tid >> 5, k = tid & 31;
    float m = -1e30f, s = 0.f;
    for (int c = 0; c < 16; ++c) {
        const float mc = ws[WA + (long)(b * 16 + c) * 64 + k];
        const float sc = ws[WA + (long)(b * 16 + c) * 64 + 32 + k];
        const float nm = fmaxf(m, mc);
        s = s * __expf(m - nm) + sc * __expf(mc - nm);
        m = nm;
    }
    ws[WB + (long)b * 64 + k]      = m;
    ws[WB + (long)b * 64 + 32 + k] = 1.f / s;
}

// ============ K2c: phi_weights = exp(logit - m) * rinv ====================
__global__ __launch_bounds__(256) void k_pw(float* __restrict__ out,
                                            const float* __restrict__ ws)
{
    const long i4 = (long)blockIdx.x * 256 + threadIdx.x;   // < 262144
    const float4 l4 = reinterpret_cast<const float4*>(out + O5)[i4];
    const long idx = i4 * 4;
    const int b  = (int)(idx >> 17);
    const int k0 = (int)(idx & 31);
    const float* mb = ws + WB + (long)b * 64;
    const float lv[4] = {l4.x, l4.y, l4.z, l4.w};
    float r[4];
#pragma unroll
    for (int j = 0; j < 4; ++j) {
        const int k = k0 + j;
        r[j] = __expf(lv[j] - mb[k]) * mb[32 + k];
    }
    reinterpret_cast<float4*>(out + O2)[i4] = make_float4(r[0], r[1], r[2], r[3]);
}

// ============ K3 v3: register-tiled soft_slots partials ====================
// Grid = B * SC; block = 4 waves x full 1024 d; lane owns 4 d x 32 k
// (acc 128). Per s: 128 FMA-instr (256cy) vs 8 broadcast pw b128 (96cy)
// + 1 coalesced global x b128. pw staged [64 s][32 k] double-buffered.
__global__ __launch_bounds__(256) void k_slots3(const float* __restrict__ x,
    const float* __restrict__ out, float* __restrict__ dst, int SC, int SLEN)
{
    __shared__ float pwl[2][64 * KK];
    const int tid  = threadIdx.x;
    const int wv   = __builtin_amdgcn_readfirstlane(tid >> 6);
    const int lane = tid & 63;
    const int blk  = blockIdx.x;
    const int sc   = blk % SC;
    const int b    = blk / SC;
    const int dbl  = wv * 256 + lane * 4;      // lane's 4-d base

    float4 acc[KK];
#pragma unroll
    for (int k = 0; k < KK; ++k) acc[k] = make_float4(0.f, 0.f, 0.f, 0.f);

    const long s0 = (long)sc * SLEN;
    const float* pw = out + O2 + ((long)b * SS + s0) * KK;
    const float* xp = x + ((long)b * SS + s0) * DD + dbl;
    const int NCH = SLEN >> 6;

    float4 r0 = *reinterpret_cast<const float4*>(pw + tid * 8);
    float4 r1 = *reinterpret_cast<const float4*>(pw + tid * 8 + 4);
    *reinterpret_cast<float4*>(&pwl[0][tid * 8])     = r0;
    *reinterpret_cast<float4*>(&pwl[0][tid * 8 + 4]) = r1;
    __syncthreads();

    for (int ch = 0; ch < NCH; ++ch) {
        const int cb = ch & 1;
        if (ch + 1 < NCH) {
            const float* pn = pw + (long)(ch + 1) * 64 * KK;
            r0 = *reinterpret_cast<const float4*>(pn + tid * 8);
            r1 = *reinterpret_cast<const float4*>(pn + tid * 8 + 4);
        }
        const float* xc = xp + (long)ch * 64 * DD;
        const float* pb = &pwl[cb][0];
#pragma unroll 2
        for (int ls = 0; ls < 64; ++ls) {
            const float4 xv = *reinterpret_cast<const float4*>(xc + (long)ls * DD);
#pragma unroll
            for (int m = 0; m < 8; ++m) {
                const float4 wq = *reinterpret_cast<const float4*>(pb + ls * KK + m * 4);
#pragma unroll
                for (int cc = 0; cc < 4; ++cc) {
                    const float pv = (cc == 0) ? wq.x : (cc == 1) ? wq.y
                                   : (cc == 2) ? wq.z : wq.w;
                    float4& av = acc[m * 4 + cc];
                    av.x = fmaf(pv, xv.x, av.x);
                    av.y = fmaf(pv, xv.y, av.y);
                    av.z = fmaf(pv, xv.z, av.z);
                    av.w = fmaf(pv, xv.w, av.w);
                }
            }
        }
        if (ch + 1 < NCH) {
            *reinterpret_cast<float4*>(&pwl[cb ^ 1][tid * 8])     = r0;
            *reinterpret_cast<float4*>(&pwl[cb ^ 1][tid * 8 + 4]) = r1;
        }
        __syncthreads();
    }
    // write partial [sc*8+b][k][d]: 1KB contiguous per wave per k
    float* o = dst + ((long)(sc * BB + b) * KK) * DD + dbl;
#pragma unroll
    for (int k = 0; k < KK; ++k)
        *reinterpret_cast<float4*>(o + (long)k * DD) = acc[k];
}

// ============ K4: reduce SC partials -> soft_slots + expert_inputs =========
__global__ __launch_bounds__(256) void k_red(const float* __restrict__ src,
                                             float* __restrict__ out, int SC)
{
    const long i4 = (long)blockIdx.x * 256 + threadIdx.x;   // < 65536
    float4 s = make_float4(0.f, 0.f, 0.f, 0.f);
    const float4* p = reinterpret_cast<const float4*>(src);
    for (int c = 0; c < SC; ++c) {
        const float4 t = p[(long)c * 65536 + i4];
        s.x += t.x; s.y += t.y; s.z += t.z; s.w += t.w;
    }
    reinterpret_cast<float4*>(out + O3)[i4] = s;
    reinterpret_cast<float4*>(out + O4)[i4] = s;
}

extern "C" void kernel_launch(void* const* d_in, const int* in_sizes, int n_in,
                              void* d_out, int out_size, void* d_ws, size_t ws_size,
                              hipStream_t stream)
{
    const float* x  = (const float*)d_in[0];
    const float* Wp = (const float*)d_in[1];
    const float* bp = (const float*)d_in[2];
    float* out = (float*)d_out;
    float* ws  = (float*)d_ws;

    const size_t wfloats = ws_size / 4;
    const long wsP_floats = 4L * 32768 * KK;   // 4.19M floats = 16.8 MB

    // ---- logits ----
    if (wfloats >= (size_t)(WC + wsP_floats)) {
        hipLaunchKernelGGL(k_logits8, dim3(256), dim3(256), 0, stream, x, Wp, ws + WC);
        hipLaunchKernelGGL(k_comb2,   dim3(128), dim3(256), 0, stream, ws + WC, bp, out, ws);
    } else {
        hipLaunchKernelGGL(k_logits4, dim3(512), dim3(256), 0, stream, x, Wp, bp, out);
        hipLaunchKernelGGL(k_smpart,  dim3(128), dim3(256), 0, stream, out, ws);
    }

    hipLaunchKernelGGL(k_smcomb, dim3(1),    dim3(256), 0, stream, ws);
    hipLaunchKernelGGL(k_pw,     dim3(1024), dim3(256), 0, stream, out, ws);

    // ---- soft slots (WC region reused after k_comb2 consumed wsP) ----
    int SC = 0;
    if      (wfloats >= (size_t)(WC + 32L * 262144)) SC = 32;
    else if (wfloats >= (size_t)(WC + 16L * 262144)) SC = 16;
    else if (wfloats >= (size_t)(WC +  8L * 262144)) SC = 8;
    else if (wfloats >= (size_t)(WC +  4L * 262144)) SC = 4;
    else if (wfloats >= (size_t)(WC +  2L * 262144)) SC = 2;
    else if (wfloats >= (size_t)(WC +  1L * 262144)) SC = 1;

    if (SC >= 1) {
        hipLaunchKernelGGL(k_slots3, dim3(BB * SC), dim3(256), 0, stream,
                           x, out, ws + WC, SC, SS / SC);
        hipLaunchKernelGGL(k_red,    dim3(256), dim3(256), 0, stream, ws + WC, out, SC);
    } else {
        hipLaunchKernelGGL(k_slots3, dim3(BB), dim3(256), 0, stream,
                           x, out, out + O3, 1, SS);
        hipLaunchKernelGGL(k_red,    dim3(256), dim3(256), 0, stream, out + O3, out, 1);
    }
}

// Round 9
// 139.482 us; speedup vs baseline: 3.2808x; 1.3908x over previous
//
#include <hip/hip_runtime.h>
#include <hip/hip_bf16.h>

#define BB 8
#define SS 4096
#define DD 1024
#define KK 32
#define EE 8
#define PP 4

// ---- output float offsets ----
#define O0 0L
#define O1 262144L
#define O2 524288L
#define O3 1572864L
#define O4 1835008L
#define O5 2097152L
#define O6 3145728L

// ---- workspace float offsets ----
#define WA 0L
#define WB 8192L
#define WC 16384L

// ============ K1 v9: register-tiled logits GEMM, 2 blocks/CU ==============
// Grid 512 = 128 token-tiles(256 tok) x 4 d-quarters(256 d). Block = 4 waves;
// wave = 64 tok x 32 k; lane (i=lane>>2, j=lane&3) = 4 tok {r*16+i} x 8 k.
// 16 chunks of 16 d. Per dq(4d): 4 x-b128 (<=2-way bank) + 8 w-b128
// (16-way bcast) vs 128 FMA -> ~10.7:1. LDS 22KB, ~113 VGPR -> 2 blk/CU.
__global__ __launch_bounds__(256) void k_logits9(const float* __restrict__ x,
    const float* __restrict__ Wp, float* __restrict__ wsP)
{
    __shared__ float xl[256][20];      // 20KB, stride 20
    __shared__ float wT[4 * 144];      // [dq][j*36 + m*4 + dd]
    const int tid  = threadIdx.x;
    const int wv   = __builtin_amdgcn_readfirstlane(tid >> 6);
    const int lane = tid & 63;
    const int i    = lane >> 2;
    const int j    = lane & 3;
    const int blk  = blockIdx.x;
    const int tile = blk >> 2, q = blk & 3;
    const long tok0 = (long)tile * 256;
    const int d0 = q * 256;
    const int srow = tid >> 2;          // stage token row 0..63 (+p*64)
    const int scol = (tid & 3) * 4;     // stage col 0..12

    float a[4][8];
#pragma unroll
    for (int r = 0; r < 4; ++r)
#pragma unroll
        for (int m = 0; m < 8; ++m) a[r][m] = 0.f;

    const int wf   = tid * 2;
    const int wd   = wf >> 5;
    const int wk   = wf & 31;
    const int wslot  = (wd >> 2) * 144 + (wk >> 3) * 36 + (wk & 7) * 4 + (wd & 3);
    const int wslot2 = (wd >> 2) * 144 + (((wk+1) & 31) >> 3) * 36 + ((wk+1) & 7) * 4 + (wd & 3);

    float4 xpf[4];
    float2 wpf;
    // ---- prefetch chunk 0 ----
#pragma unroll
    for (int p = 0; p < 4; ++p)
        xpf[p] = *reinterpret_cast<const float4*>(
            x + (tok0 + srow + p * 64) * DD + d0 + scol);
    wpf = *reinterpret_cast<const float2*>(Wp + (long)(d0 + wd) * KK + wk);

    for (int c = 0; c < 16; ++c) {
        // ---- commit staged regs to LDS ----
#pragma unroll
        for (int p = 0; p < 4; ++p)
            *reinterpret_cast<float4*>(&xl[srow + p * 64][scol]) = xpf[p];
        wT[wslot]  = wpf.x;
        wT[wslot2] = wpf.y;
        __syncthreads();
        // ---- prefetch next chunk ----
        if (c < 15) {
            const long db = (long)d0 + (c + 1) * 16;
#pragma unroll
            for (int p = 0; p < 4; ++p)
                xpf[p] = *reinterpret_cast<const float4*>(
                    x + (tok0 + srow + p * 64) * DD + db + scol);
            wpf = *reinterpret_cast<const float2*>(Wp + (db + wd) * KK + wk);
        }
        // ---- compute 16 d = 4 dq steps ----
#pragma unroll
        for (int dq = 0; dq < 4; ++dq) {
            float4 xv[4];
#pragma unroll
            for (int r = 0; r < 4; ++r)
                xv[r] = *reinterpret_cast<const float4*>(&xl[wv * 64 + r * 16 + i][dq * 4]);
            float4 wq[8];
#pragma unroll
            for (int m = 0; m < 8; ++m)
                wq[m] = *reinterpret_cast<const float4*>(&wT[dq * 144 + j * 36 + m * 4]);
#pragma unroll
            for (int r = 0; r < 4; ++r)
#pragma unroll
                for (int m = 0; m < 8; ++m) {
                    a[r][m] = fmaf(xv[r].x, wq[m].x, a[r][m]);
                    a[r][m] = fmaf(xv[r].y, wq[m].y, a[r][m]);
                    a[r][m] = fmaf(xv[r].z, wq[m].z, a[r][m]);
                    a[r][m] = fmaf(xv[r].w, wq[m].w, a[r][m]);
                }
        }
        __syncthreads();
    }

    // ---- partial store: wsP[q][token][32k] ----
#pragma unroll
    for (int r = 0; r < 4; ++r) {
        const long t = tok0 + wv * 64 + r * 16 + i;
        float* o = wsP + ((long)q * 32768 + t) * KK + j * 8;
        *reinterpret_cast<float4*>(o)     = make_float4(a[r][0], a[r][1], a[r][2], a[r][3]);
        *reinterpret_cast<float4*>(o + 4) = make_float4(a[r][4], a[r][5], a[r][6], a[r][7]);
    }
}

// ============ K1b: combine 4 d-quarter partials + bias + epilogue + stats ==
__global__ __launch_bounds__(256) void k_comb2(const float* __restrict__ wsP,
    const float* __restrict__ bp, float* __restrict__ out, float* __restrict__ ws)
{
    const int blk = blockIdx.x;
    const int tid = threadIdx.x;
    const int wv  = __builtin_amdgcn_readfirstlane(tid >> 6);
    const long g  = (long)blk * 256 + tid;
    float acc[KK];
#pragma unroll
    for (int k = 0; k < KK; ++k) acc[k] = bp[k];
#pragma unroll
    for (int q = 0; q < 4; ++q) {
        const float4* p = reinterpret_cast<const float4*>(wsP + ((long)q * 32768 + g) * KK);
#pragma unroll
        for (int m = 0; m < 8; ++m) {
            const float4 v = p[m];
            acc[4*m]   += v.x;
            acc[4*m+1] += v.y;
            acc[4*m+2] += v.z;
            acc[4*m+3] += v.w;
        }
    }
    float4* pl = reinterpret_cast<float4*>(out + O5 + g * KK);
#pragma unroll
    for (int m = 0; m < 8; ++m)
        pl[m] = make_float4(acc[4*m], acc[4*m+1], acc[4*m+2], acc[4*m+3]);
    float rg[KK];
#pragma unroll
    for (int e = 0; e < EE; ++e) {
        const float mx = fmaxf(fmaxf(acc[4*e], acc[4*e+1]), fmaxf(acc[4*e+2], acc[4*e+3]));
        float s = 0.f;
#pragma unroll
        for (int p = 0; p < PP; ++p) { rg[4*e+p] = __expf(acc[4*e+p] - mx); s += rg[4*e+p]; }
        const float ri = 1.f / s;
#pragma unroll
        for (int p = 0; p < PP; ++p) rg[4*e+p] *= ri;
    }
    float4* prg = reinterpret_cast<float4*>(out + O6 + g * KK);
#pragma unroll
    for (int m = 0; m < 8; ++m)
        prg[m] = make_float4(rg[4*m], rg[4*m+1], rg[4*m+2], rg[4*m+3]);
    float4* pew = reinterpret_cast<float4*>(out + O0 + g * EE);
    pew[0] = make_float4(0.125f, 0.125f, 0.125f, 0.125f);
    pew[1] = make_float4(0.125f, 0.125f, 0.125f, 0.125f);
    float4* pei = reinterpret_cast<float4*>(out + O1 + g * EE);
    pei[0] = make_float4(0.f, 1.f, 2.f, 3.f);
    pei[1] = make_float4(4.f, 5.f, 6.f, 7.f);

    float m[KK];
#pragma unroll
    for (int k = 0; k < KK; ++k) m[k] = acc[k];
    for (int off = 1; off < 64; off <<= 1) {
#pragma unroll
        for (int k = 0; k < KK; ++k) m[k] = fmaxf(m[k], __shfl_xor(m[k], off));
    }
    __shared__ float lm[4][KK];
    __shared__ float lsum[4][KK];
    if ((tid & 63) == 0) {
#pragma unroll
        for (int k = 0; k < KK; ++k) lm[wv][k] = m[k];
    }
    __syncthreads();
#pragma unroll
    for (int k = 0; k < KK; ++k)
        m[k] = fmaxf(fmaxf(lm[0][k], lm[1][k]), fmaxf(lm[2][k], lm[3][k]));
    float sv[KK];
#pragma unroll
    for (int k = 0; k < KK; ++k) sv[k] = __expf(acc[k] - m[k]);
    for (int off = 1; off < 64; off <<= 1) {
#pragma unroll
        for (int k = 0; k < KK; ++k) sv[k] += __shfl_xor(sv[k], off);
    }
    if ((tid & 63) == 0) {
#pragma unroll
        for (int k = 0; k < KK; ++k) lsum[wv][k] = sv[k];
    }
    __syncthreads();
    if (tid == 0) {
#pragma unroll
        for (int k = 0; k < KK; ++k) {
            ws[WA + (long)blk * 64 + k]      = m[k];
            ws[WA + (long)blk * 64 + 32 + k] = lsum[0][k] + lsum[1][k] + lsum[2][k] + lsum[3][k];
        }
    }
}

// ============ K1 fallback (direct) + stats kernel, if ws is tiny ===========
__global__ __launch_bounds__(256) void k_logits4(const float* __restrict__ x,
    const float* __restrict__ Wp, const float* __restrict__ bp,
    float* __restrict__ out)
{
    __shared__ float xl[2][64][68];
    __shared__ float wl[2][64][32];
    const int tid  = threadIdx.x;
    const int wv   = __builtin_amdgcn_readfirstlane(tid >> 6);
    const int lane = tid & 63;
    const long tok0 = (long)blockIdx.x * 64;
    const long g   = tok0 + lane;
    const int sr = tid >> 2;
    const int sco = (tid & 3) * 4;
    float acc[8];
#pragma unroll
    for (int j = 0; j < 8; ++j) acc[j] = 0.f;
    float4 xr[4], wr[2];
#pragma unroll
    for (int j = 0; j < 4; ++j)
        xr[j] = *reinterpret_cast<const float4*>(x + (tok0 + sr) * DD + sco + j * 16);
#pragma unroll
    for (int j = 0; j < 2; ++j)
        wr[j] = *reinterpret_cast<const float4*>(Wp + tid * 8 + j * 4);
#pragma unroll
    for (int j = 0; j < 4; ++j)
        *reinterpret_cast<float4*>(&xl[0][sr][sco + j * 16]) = xr[j];
#pragma unroll
    for (int j = 0; j < 2; ++j)
        *reinterpret_cast<float4*>(&wl[0][0][0] + tid * 8 + j * 4) = wr[j];
    __syncthreads();
    for (int c = 0; c < 16; ++c) {
        const int cb = c & 1;
        if (c < 15) {
            const long dg = (long)(c + 1) * 64;
#pragma unroll
            for (int j = 0; j < 4; ++j)
                xr[j] = *reinterpret_cast<const float4*>(
                    x + (tok0 + sr) * DD + dg + sco + j * 16);
#pragma unroll
            for (int j = 0; j < 2; ++j)
                wr[j] = *reinterpret_cast<const float4*>(Wp + dg * KK + tid * 8 + j * 4);
        }
        const float* xb = &xl[cb][lane][0];
        const float* wb = &wl[cb][0][0] + wv * 8;
#pragma unroll 4
        for (int dq = 0; dq < 16; ++dq) {
            const float4 xv = *reinterpret_cast<const float4*>(xb + dq * 4);
#pragma unroll
            for (int dd = 0; dd < 4; ++dd) {
                const float xs = (dd == 0) ? xv.x : (dd == 1) ? xv.y
                               : (dd == 2) ? xv.z : xv.w;
                const float4 w0 = *reinterpret_cast<const float4*>(wb + (dq * 4 + dd) * 32);
                const float4 w1 = *reinterpret_cast<const float4*>(wb + (dq * 4 + dd) * 32 + 4);
                acc[0] = fmaf(xs, w0.x, acc[0]);
                acc[1] = fmaf(xs, w0.y, acc[1]);
                acc[2] = fmaf(xs, w0.z, acc[2]);
                acc[3] = fmaf(xs, w0.w, acc[3]);
                acc[4] = fmaf(xs, w1.x, acc[4]);
                acc[5] = fmaf(xs, w1.y, acc[5]);
                acc[6] = fmaf(xs, w1.z, acc[6]);
                acc[7] = fmaf(xs, w1.w, acc[7]);
            }
        }
        if (c < 15) {
#pragma unroll
            for (int j = 0; j < 4; ++j)
                *reinterpret_cast<float4*>(&xl[cb ^ 1][sr][sco + j * 16]) = xr[j];
#pragma unroll
            for (int j = 0; j < 2; ++j)
                *reinterpret_cast<float4*>(&wl[cb ^ 1][0][0] + tid * 8 + j * 4) = wr[j];
        }
        __syncthreads();
    }
#pragma unroll
    for (int j = 0; j < 8; ++j) acc[j] += bp[wv * 8 + j];
    float* o5 = out + O5 + g * KK + wv * 8;
    *reinterpret_cast<float4*>(o5)     = make_float4(acc[0], acc[1], acc[2], acc[3]);
    *reinterpret_cast<float4*>(o5 + 4) = make_float4(acc[4], acc[5], acc[6], acc[7]);
    float rg[8];
#pragma unroll
    for (int e = 0; e < 2; ++e) {
        const float* aa = &acc[e * 4];
        const float m = fmaxf(fmaxf(aa[0], aa[1]), fmaxf(aa[2], aa[3]));
        float s = 0.f;
#pragma unroll
        for (int p = 0; p < PP; ++p) { rg[e*4+p] = __expf(aa[p] - m); s += rg[e*4+p]; }
        const float ri = 1.f / s;
#pragma unroll
        for (int p = 0; p < PP; ++p) rg[e*4+p] *= ri;
    }
    float* o6 = out + O6 + g * KK + wv * 8;
    *reinterpret_cast<float4*>(o6)     = make_float4(rg[0], rg[1], rg[2], rg[3]);
    *reinterpret_cast<float4*>(o6 + 4) = make_float4(rg[4], rg[5], rg[6], rg[7]);
    if (wv == 0) {
        float4* p = reinterpret_cast<float4*>(out + O0 + g * EE);
        p[0] = make_float4(0.125f, 0.125f, 0.125f, 0.125f);
        p[1] = make_float4(0.125f, 0.125f, 0.125f, 0.125f);
    } else if (wv == 1) {
        float4* p = reinterpret_cast<float4*>(out + O1 + g * EE);
        p[0] = make_float4(0.f, 1.f, 2.f, 3.f);
        p[1] = make_float4(4.f, 5.f, 6.f, 7.f);
    }
}

__global__ __launch_bounds__(256) void k_smpart(const float* __restrict__ out,
                                                float* __restrict__ ws)
{
    const int blk = blockIdx.x;
    const int tid = threadIdx.x;
    const int wv  = __builtin_amdgcn_readfirstlane(tid >> 6);
    const int b = blk >> 4, sc = blk & 15;
    const long s  = (long)sc * 256 + tid;
    const float* row = out + O5 + ((long)b * SS + s) * KK;
    float v[KK];
    const float4* r4 = reinterpret_cast<const float4*>(row);
#pragma unroll
    for (int q = 0; q < 8; ++q) {
        const float4 t = r4[q];
        v[4*q] = t.x; v[4*q+1] = t.y; v[4*q+2] = t.z; v[4*q+3] = t.w;
    }
    float m[KK];
#pragma unroll
    for (int k = 0; k < KK; ++k) m[k] = v[k];
    for (int off = 1; off < 64; off <<= 1) {
#pragma unroll
        for (int k = 0; k < KK; ++k) m[k] = fmaxf(m[k], __shfl_xor(m[k], off));
    }
    __shared__ float lm[4][KK];
    __shared__ float lsum[4][KK];
    if ((tid & 63) == 0) {
#pragma unroll
        for (int k = 0; k < KK; ++k) lm[wv][k] = m[k];
    }
    __syncthreads();
#pragma unroll
    for (int k = 0; k < KK; ++k)
        m[k] = fmaxf(fmaxf(lm[0][k], lm[1][k]), fmaxf(lm[2][k], lm[3][k]));
    float sv[KK];
#pragma unroll
    for (int k = 0; k < KK; ++k) sv[k] = __expf(v[k] - m[k]);
    for (int off = 1; off < 64; off <<= 1) {
#pragma unroll
        for (int k = 0; k < KK; ++k) sv[k] += __shfl_xor(sv[k], off);
    }
    if ((tid & 63) == 0) {
#pragma unroll
        for (int k = 0; k < KK; ++k) lsum[wv][k] = sv[k];
    }
    __syncthreads();
    if (tid == 0) {
#pragma unroll
        for (int k = 0; k < KK; ++k) {
            ws[WA + (long)blk * 64 + k]      = m[k];
            ws[WA + (long)blk * 64 + 32 + k] = lsum[0][k] + lsum[1][k] + lsum[2][k] + lsum[3][k];
        }
    }
}

__global__ __launch_bounds__(256) void k_smcomb(float* __restrict__ ws)
{
    const int tid = threadIdx.x;
    const int b = tid >> 5, k = tid & 31;
    float m = -1e30f, s = 0.f;
    for (int c = 0; c < 16; ++c) {
        const float mc = ws[WA + (long)(b * 16 + c) * 64 + k];
        const float sc = ws[WA + (long)(b * 16 + c) * 64 + 32 + k];
        const float nm = fmaxf(m, mc);
        s = s * __expf(m - nm) + sc * __expf(mc - nm);
        m = nm;
    }
    ws[WB + (long)b * 64 + k]      = m;
    ws[WB + (long)b * 64 + 32 + k] = 1.f / s;
}

__global__ __launch_bounds__(256) void k_pw(float* __restrict__ out,
                                            const float* __restrict__ ws)
{
    const long i4 = (long)blockIdx.x * 256 + threadIdx.x;
    const float4 l4 = reinterpret_cast<const float4*>(out + O5)[i4];
    const long idx = i4 * 4;
    const int b  = (int)(idx >> 17);
    const int k0 = (int)(idx & 31);
    const float* mb = ws + WB + (long)b * 64;
    const float lv[4] = {l4.x, l4.y, l4.z, l4.w};
    float r[4];
#pragma unroll
    for (int j = 0; j < 4; ++j) {
        const int k = k0 + j;
        r[j] = __expf(lv[j] - mb[k]) * mb[32 + k];
    }
    reinterpret_cast<float4*>(out + O2)[i4] = make_float4(r[0], r[1], r[2], r[3]);
}

// ============ K3 (k_slots2, proven R5/R6): pw staged in LDS ================
__global__ __launch_bounds__(256) void k_slots2(const float* __restrict__ x,
    const float* __restrict__ out, float* __restrict__ dst, int SC, int SLEN)
{
    __shared__ float pwl[2][64 * KK];
    const int tid = threadIdx.x;
    const int blk = blockIdx.x;
    const int sc  = blk % SC;
    const int t2  = blk / SC;
    const int dc  = t2 & 3;
    const int b   = t2 >> 2;
    const int d   = dc * 256 + tid;
    float acc[KK];
#pragma unroll
    for (int k = 0; k < KK; ++k) acc[k] = 0.f;
    const long s0 = (long)sc * SLEN;
    const float* pw = out + O2 + ((long)b * SS + s0) * KK;
    const float* xp = x + ((long)b * SS + s0) * DD + d;
    const int NCH = SLEN >> 6;

    float4 r0 = *reinterpret_cast<const float4*>(pw + tid * 8);
    float4 r1 = *reinterpret_cast<const float4*>(pw + tid * 8 + 4);
    *reinterpret_cast<float4*>(&pwl[0][tid * 8])     = r0;
    *reinterpret_cast<float4*>(&pwl[0][tid * 8 + 4]) = r1;
    __syncthreads();

    for (int ch = 0; ch < NCH; ++ch) {
        const int cb = ch & 1;
        if (ch + 1 < NCH) {
            const float* pn = pw + (long)(ch + 1) * 64 * KK;
            r0 = *reinterpret_cast<const float4*>(pn + tid * 8);
            r1 = *reinterpret_cast<const float4*>(pn + tid * 8 + 4);
        }
        const float* xc = xp + (long)ch * 64 * DD;
        const float* pb = &pwl[cb][0];
#pragma unroll 8
        for (int i = 0; i < 64; ++i) {
            const float xv = xc[(long)i * DD];
#pragma unroll
            for (int q = 0; q < 8; ++q) {
                const float4 w = *reinterpret_cast<const float4*>(pb + i * KK + q * 4);
                acc[4*q]   = fmaf(w.x, xv, acc[4*q]);
                acc[4*q+1] = fmaf(w.y, xv, acc[4*q+1]);
                acc[4*q+2] = fmaf(w.z, xv, acc[4*q+2]);
                acc[4*q+3] = fmaf(w.w, xv, acc[4*q+3]);
            }
        }
        if (ch + 1 < NCH) {
            *reinterpret_cast<float4*>(&pwl[cb ^ 1][tid * 8])     = r0;
            *reinterpret_cast<float4*>(&pwl[cb ^ 1][tid * 8 + 4]) = r1;
        }
        __syncthreads();
    }
    float* o = dst + ((long)(sc * BB + b) * KK) * DD + d;
#pragma unroll
    for (int k = 0; k < KK; ++k) o[(long)k * DD] = acc[k];
}

// ============ K4: reduce SC partials -> soft_slots + expert_inputs =========
__global__ __launch_bounds__(256) void k_red(const float* __restrict__ src,
                                             float* __restrict__ out, int SC)
{
    const long i4 = (long)blockIdx.x * 256 + threadIdx.x;
    float4 s = make_float4(0.f, 0.f, 0.f, 0.f);
    const float4* p = reinterpret_cast<const float4*>(src);
    for (int c = 0; c < SC; ++c) {
        const float4 t = p[(long)c * 65536 + i4];
        s.x += t.x; s.y += t.y; s.z += t.z; s.w += t.w;
    }
    reinterpret_cast<float4*>(out + O3)[i4] = s;
    reinterpret_cast<float4*>(out + O4)[i4] = s;
}

extern "C" void kernel_launch(void* const* d_in, const int* in_sizes, int n_in,
                              void* d_out, int out_size, void* d_ws, size_t ws_size,
                              hipStream_t stream)
{
    const float* x  = (const float*)d_in[0];
    const float* Wp = (const float*)d_in[1];
    const float* bp = (const float*)d_in[2];
    float* out = (float*)d_out;
    float* ws  = (float*)d_ws;

    const size_t wfloats = ws_size / 4;
    const long wsP_floats = 4L * 32768 * KK;   // 16.8 MB

    if (wfloats >= (size_t)(WC + wsP_floats)) {
        hipLaunchKernelGGL(k_logits9, dim3(512), dim3(256), 0, stream, x, Wp, ws + WC);
        hipLaunchKernelGGL(k_comb2,   dim3(128), dim3(256), 0, stream, ws + WC, bp, out, ws);
    } else {
        hipLaunchKernelGGL(k_logits4, dim3(512), dim3(256), 0, stream, x, Wp, bp, out);
        hipLaunchKernelGGL(k_smpart,  dim3(128), dim3(256), 0, stream, out, ws);
    }

    hipLaunchKernelGGL(k_smcomb, dim3(1),    dim3(256), 0, stream, ws);
    hipLaunchKernelGGL(k_pw,     dim3(1024), dim3(256), 0, stream, out, ws);

    int SC = 0;
    if      (wfloats >= (size_t)(WC + 32L * 262144)) SC = 32;
    else if (wfloats >= (size_t)(WC + 16L * 262144)) SC = 16;
    else if (wfloats >= (size_t)(WC +  8L * 262144)) SC = 8;
    else if (wfloats >= (size_t)(WC +  4L * 262144)) SC = 4;
    else if (wfloats >= (size_t)(WC +  2L * 262144)) SC = 2;
    else if (wfloats >= (size_t)(WC +  1L * 262144)) SC = 1;

    if (SC >= 1) {
        hipLaunchKernelGGL(k_slots2, dim3(BB * 4 * SC), dim3(256), 0, stream,
                           x, out, ws + WC, SC, SS / SC);
        hipLaunchKernelGGL(k_red,    dim3(256), dim3(256), 0, stream, ws + WC, out, SC);
    } else {
        hipLaunchKernelGGL(k_slots2, dim3(BB * 4), dim3(256), 0, stream,
                           x, out, out + O3, 1, SS);
        hipLaunchKernelGGL(k_red,    dim3(256), dim3(256), 0, stream, out + O3, out, 1);
    }
}

// Round 10
// 107.593 us; speedup vs baseline: 4.2532x; 1.2964x over previous
//
#include <hip/hip_runtime.h>
#include <hip/hip_bf16.h>

#define BB 8
#define SS 4096
#define DD 1024
#define KK 32
#define EE 8
#define PP 4

// ---- output float offsets ----
#define O0 0L
#define O1 262144L
#define O2 524288L
#define O3 1572864L
#define O4 1835008L
#define O5 2097152L
#define O6 3145728L

// ---- workspace float offsets ----
#define WA 0L
#define WB 8192L
#define WC 16384L
#define WPKH (WC + 2097152L)     // W packed hi: 32768 ushort = 16384 floats
#define WPKL (WPKH + 16384L)     // W packed lo
#define WEND (WPKL + 16384L)

typedef __attribute__((ext_vector_type(8))) short short8v;
typedef __attribute__((ext_vector_type(4))) float f32x4;

__device__ __forceinline__ unsigned short f2bf(float f) {
    unsigned u = __builtin_bit_cast(unsigned, f);
    unsigned r = (u + 0x7FFFu + ((u >> 16) & 1u)) >> 16;
    return (unsigned short)r;
}
__device__ __forceinline__ float bf2f(unsigned short h) {
    return __builtin_bit_cast(float, (unsigned)h << 16);
}

// ============ K0: pack W into B^T-fragment order, bf16 hi+lo ==============
// wpk[ks 0..31][tile 0..1][lane 0..63][j 0..7] = W[ks*32+(lane>>4)*8+j][tile*16+(lane&15)]
__global__ __launch_bounds__(256) void k_wprep(const float* __restrict__ Wp,
    unsigned short* __restrict__ wh, unsigned short* __restrict__ wl)
{
    const int t  = blockIdx.x * 256 + threadIdx.x;    // 0..4095
    const int l  = t & 63;
    const int tt = (t >> 6) & 1;
    const int ks = t >> 7;
    const int col = tt * 16 + (l & 15);
    const int dbase = ks * 32 + (l >> 4) * 8;
    const long obase = ((long)(ks * 2 + tt) * 64 + l) * 8;
#pragma unroll
    for (int j = 0; j < 8; ++j) {
        const float w = Wp[(long)(dbase + j) * KK + col];
        const unsigned short h = f2bf(w);
        const float lo = w - bf2f(h);
        wh[obase + j] = h;
        wl[obase + j] = f2bf(lo);
    }
}

// ============ K1 vMFMA: logits GEMM on matrix cores, no LDS, no barriers ===
// Grid 1024 = 512 token-tiles(64 tok) x 2 K-halves. Block = 4 waves; wave =
// 16 tokens x 32 k (2 n-tiles). Lane: A-row = tok0w+(lane&15), 8 consecutive
// d at kg*8. fp32 x read direct from global (16 rows x 128B/instr), split to
// bf16 hi+lo in regs; B frags pre-packed (L2-hot). 6 MFMA/kstep (Karatsuba:
// hh + lh + hl ~ fp32 accuracy). fp32 partials [half][tok][32k] to ws.
__global__ __launch_bounds__(256) void k_logits_mfma(const float* __restrict__ x,
    const unsigned short* __restrict__ wh, const unsigned short* __restrict__ wl,
    float* __restrict__ wsP)
{
    const int tid  = threadIdx.x;
    const int wv   = tid >> 6;
    const int lane = tid & 63;
    const int blk  = blockIdx.x;
    const int tile = blk >> 1, half = blk & 1;
    const long tokw = (long)tile * 64 + wv * 16;      // wave's 16-token base
    const int mrow = lane & 15;
    const int kg   = lane >> 4;

    const float* xr = x + (tokw + mrow) * DD + half * 512 + kg * 8;
    const uint4* bh = reinterpret_cast<const uint4*>(wh) + (long)half * 16 * 2 * 64 + lane;
    const uint4* bl = reinterpret_cast<const uint4*>(wl) + (long)half * 16 * 2 * 64 + lane;

    f32x4 acc0 = {0.f, 0.f, 0.f, 0.f};
    f32x4 acc1 = {0.f, 0.f, 0.f, 0.f};

#pragma unroll 4
    for (int s = 0; s < 16; ++s) {
        const float4 u0 = *reinterpret_cast<const float4*>(xr + s * 32);
        const float4 u1 = *reinterpret_cast<const float4*>(xr + s * 32 + 4);
        const short8v b0h = __builtin_bit_cast(short8v, bh[(long)(s * 2    ) * 64]);
        const short8v b1h = __builtin_bit_cast(short8v, bh[(long)(s * 2 + 1) * 64]);
        const short8v b0l = __builtin_bit_cast(short8v, bl[(long)(s * 2    ) * 64]);
        const short8v b1l = __builtin_bit_cast(short8v, bl[(long)(s * 2 + 1) * 64]);

        const float xf[8] = {u0.x, u0.y, u0.z, u0.w, u1.x, u1.y, u1.z, u1.w};
        short8v ah, al;
#pragma unroll
        for (int j = 0; j < 8; ++j) {
            const unsigned short h = f2bf(xf[j]);
            ah[j] = (short)h;
            al[j] = (short)f2bf(xf[j] - bf2f(h));
        }
        acc0 = __builtin_amdgcn_mfma_f32_16x16x32_bf16(ah, b0h, acc0, 0, 0, 0);
        acc1 = __builtin_amdgcn_mfma_f32_16x16x32_bf16(ah, b1h, acc1, 0, 0, 0);
        acc0 = __builtin_amdgcn_mfma_f32_16x16x32_bf16(al, b0h, acc0, 0, 0, 0);
        acc1 = __builtin_amdgcn_mfma_f32_16x16x32_bf16(al, b1h, acc1, 0, 0, 0);
        acc0 = __builtin_amdgcn_mfma_f32_16x16x32_bf16(ah, b0l, acc0, 0, 0, 0);
        acc1 = __builtin_amdgcn_mfma_f32_16x16x32_bf16(ah, b1l, acc1, 0, 0, 0);
    }

    // C/D layout: col = lane&15, row = (lane>>4)*4 + reg  [m89]
#pragma unroll
    for (int r = 0; r < 4; ++r) {
        const long tok = tokw + kg * 4 + r;
        float* o = wsP + ((long)half * 32768 + tok) * KK + mrow;
        o[0]  = acc0[r];
        o[16] = acc1[r];
    }
}

// ============ K1b: combine 2 K-half partials + bias + epilogue + sm stats ==
__global__ __launch_bounds__(256) void k_comb2(const float* __restrict__ wsP,
    const float* __restrict__ bp, float* __restrict__ out, float* __restrict__ ws)
{
    const int blk = blockIdx.x;            // = b*16 + sc (256-token chunk)
    const int tid = threadIdx.x;
    const int wv  = __builtin_amdgcn_readfirstlane(tid >> 6);
    const long g  = (long)blk * 256 + tid;
    float acc[KK];
#pragma unroll
    for (int k = 0; k < KK; ++k) acc[k] = bp[k];
#pragma unroll
    for (int h = 0; h < 2; ++h) {
        const float4* p = reinterpret_cast<const float4*>(wsP + ((long)h * 32768 + g) * KK);
#pragma unroll
        for (int m = 0; m < 8; ++m) {
            const float4 v = p[m];
            acc[4*m]   += v.x;
            acc[4*m+1] += v.y;
            acc[4*m+2] += v.z;
            acc[4*m+3] += v.w;
        }
    }
    float4* pl = reinterpret_cast<float4*>(out + O5 + g * KK);
#pragma unroll
    for (int m = 0; m < 8; ++m)
        pl[m] = make_float4(acc[4*m], acc[4*m+1], acc[4*m+2], acc[4*m+3]);
    float rg[KK];
#pragma unroll
    for (int e = 0; e < EE; ++e) {
        const float mx = fmaxf(fmaxf(acc[4*e], acc[4*e+1]), fmaxf(acc[4*e+2], acc[4*e+3]));
        float s = 0.f;
#pragma unroll
        for (int p = 0; p < PP; ++p) { rg[4*e+p] = __expf(acc[4*e+p] - mx); s += rg[4*e+p]; }
        const float ri = 1.f / s;
#pragma unroll
        for (int p = 0; p < PP; ++p) rg[4*e+p] *= ri;
    }
    float4* prg = reinterpret_cast<float4*>(out + O6 + g * KK);
#pragma unroll
    for (int m = 0; m < 8; ++m)
        prg[m] = make_float4(rg[4*m], rg[4*m+1], rg[4*m+2], rg[4*m+3]);
    float4* pew = reinterpret_cast<float4*>(out + O0 + g * EE);
    pew[0] = make_float4(0.125f, 0.125f, 0.125f, 0.125f);
    pew[1] = make_float4(0.125f, 0.125f, 0.125f, 0.125f);
    float4* pei = reinterpret_cast<float4*>(out + O1 + g * EE);
    pei[0] = make_float4(0.f, 1.f, 2.f, 3.f);
    pei[1] = make_float4(4.f, 5.f, 6.f, 7.f);

    float m[KK];
#pragma unroll
    for (int k = 0; k < KK; ++k) m[k] = acc[k];
    for (int off = 1; off < 64; off <<= 1) {
#pragma unroll
        for (int k = 0; k < KK; ++k) m[k] = fmaxf(m[k], __shfl_xor(m[k], off));
    }
    __shared__ float lm[4][KK];
    __shared__ float lsum[4][KK];
    if ((tid & 63) == 0) {
#pragma unroll
        for (int k = 0; k < KK; ++k) lm[wv][k] = m[k];
    }
    __syncthreads();
#pragma unroll
    for (int k = 0; k < KK; ++k)
        m[k] = fmaxf(fmaxf(lm[0][k], lm[1][k]), fmaxf(lm[2][k], lm[3][k]));
    float sv[KK];
#pragma unroll
    for (int k = 0; k < KK; ++k) sv[k] = __expf(acc[k] - m[k]);
    for (int off = 1; off < 64; off <<= 1) {
#pragma unroll
        for (int k = 0; k < KK; ++k) sv[k] += __shfl_xor(sv[k], off);
    }
    if ((tid & 63) == 0) {
#pragma unroll
        for (int k = 0; k < KK; ++k) lsum[wv][k] = sv[k];
    }
    __syncthreads();
    if (tid == 0) {
#pragma unroll
        for (int k = 0; k < KK; ++k) {
            ws[WA + (long)blk * 64 + k]      = m[k];
            ws[WA + (long)blk * 64 + 32 + k] = lsum[0][k] + lsum[1][k] + lsum[2][k] + lsum[3][k];
        }
    }
}

// ============ K1 fallback (direct fp32) + stats kernel, if ws is tiny ======
__global__ __launch_bounds__(256) void k_logits4(const float* __restrict__ x,
    const float* __restrict__ Wp, const float* __restrict__ bp,
    float* __restrict__ out)
{
    __shared__ float xl[2][64][68];
    __shared__ float wl[2][64][32];
    const int tid  = threadIdx.x;
    const int wv   = __builtin_amdgcn_readfirstlane(tid >> 6);
    const int lane = tid & 63;
    const long tok0 = (long)blockIdx.x * 64;
    const long g   = tok0 + lane;
    const int sr = tid >> 2;
    const int sco = (tid & 3) * 4;
    float acc[8];
#pragma unroll
    for (int j = 0; j < 8; ++j) acc[j] = 0.f;
    float4 xr[4], wr[2];
#pragma unroll
    for (int j = 0; j < 4; ++j)
        xr[j] = *reinterpret_cast<const float4*>(x + (tok0 + sr) * DD + sco + j * 16);
#pragma unroll
    for (int j = 0; j < 2; ++j)
        wr[j] = *reinterpret_cast<const float4*>(Wp + tid * 8 + j * 4);
#pragma unroll
    for (int j = 0; j < 4; ++j)
        *reinterpret_cast<float4*>(&xl[0][sr][sco + j * 16]) = xr[j];
#pragma unroll
    for (int j = 0; j < 2; ++j)
        *reinterpret_cast<float4*>(&wl[0][0][0] + tid * 8 + j * 4) = wr[j];
    __syncthreads();
    for (int c = 0; c < 16; ++c) {
        const int cb = c & 1;
        if (c < 15) {
            const long dg = (long)(c + 1) * 64;
#pragma unroll
            for (int j = 0; j < 4; ++j)
                xr[j] = *reinterpret_cast<const float4*>(
                    x + (tok0 + sr) * DD + dg + sco + j * 16);
#pragma unroll
            for (int j = 0; j < 2; ++j)
                wr[j] = *reinterpret_cast<const float4*>(Wp + dg * KK + tid * 8 + j * 4);
        }
        const float* xb = &xl[cb][lane][0];
        const float* wb = &wl[cb][0][0] + wv * 8;
#pragma unroll 4
        for (int dq = 0; dq < 16; ++dq) {
            const float4 xv = *reinterpret_cast<const float4*>(xb + dq * 4);
#pragma unroll
            for (int dd = 0; dd < 4; ++dd) {
                const float xs = (dd == 0) ? xv.x : (dd == 1) ? xv.y
                               : (dd == 2) ? xv.z : xv.w;
                const float4 w0 = *reinterpret_cast<const float4*>(wb + (dq * 4 + dd) * 32);
                const float4 w1 = *reinterpret_cast<const float4*>(wb + (dq * 4 + dd) * 32 + 4);
                acc[0] = fmaf(xs, w0.x, acc[0]);
                acc[1] = fmaf(xs, w0.y, acc[1]);
                acc[2] = fmaf(xs, w0.z, acc[2]);
                acc[3] = fmaf(xs, w0.w, acc[3]);
                acc[4] = fmaf(xs, w1.x, acc[4]);
                acc[5] = fmaf(xs, w1.y, acc[5]);
                acc[6] = fmaf(xs, w1.z, acc[6]);
                acc[7] = fmaf(xs, w1.w, acc[7]);
            }
        }
        if (c < 15) {
#pragma unroll
            for (int j = 0; j < 4; ++j)
                *reinterpret_cast<float4*>(&xl[cb ^ 1][sr][sco + j * 16]) = xr[j];
#pragma unroll
            for (int j = 0; j < 2; ++j)
                *reinterpret_cast<float4*>(&wl[cb ^ 1][0][0] + tid * 8 + j * 4) = wr[j];
        }
        __syncthreads();
    }
#pragma unroll
    for (int j = 0; j < 8; ++j) acc[j] += bp[wv * 8 + j];
    float* o5 = out + O5 + g * KK + wv * 8;
    *reinterpret_cast<float4*>(o5)     = make_float4(acc[0], acc[1], acc[2], acc[3]);
    *reinterpret_cast<float4*>(o5 + 4) = make_float4(acc[4], acc[5], acc[6], acc[7]);
    float rg[8];
#pragma unroll
    for (int e = 0; e < 2; ++e) {
        const float* aa = &acc[e * 4];
        const float m = fmaxf(fmaxf(aa[0], aa[1]), fmaxf(aa[2], aa[3]));
        float s = 0.f;
#pragma unroll
        for (int p = 0; p < PP; ++p) { rg[e*4+p] = __expf(aa[p] - m); s += rg[e*4+p]; }
        const float ri = 1.f / s;
#pragma unroll
        for (int p = 0; p < PP; ++p) rg[e*4+p] *= ri;
    }
    float* o6 = out + O6 + g * KK + wv * 8;
    *reinterpret_cast<float4*>(o6)     = make_float4(rg[0], rg[1], rg[2], rg[3]);
    *reinterpret_cast<float4*>(o6 + 4) = make_float4(rg[4], rg[5], rg[6], rg[7]);
    if (wv == 0) {
        float4* p = reinterpret_cast<float4*>(out + O0 + g * EE);
        p[0] = make_float4(0.125f, 0.125f, 0.125f, 0.125f);
        p[1] = make_float4(0.125f, 0.125f, 0.125f, 0.125f);
    } else if (wv == 1) {
        float4* p = reinterpret_cast<float4*>(out + O1 + g * EE);
        p[0] = make_float4(0.f, 1.f, 2.f, 3.f);
        p[1] = make_float4(4.f, 5.f, 6.f, 7.f);
    }
}

__global__ __launch_bounds__(256) void k_smpart(const float* __restrict__ out,
                                                float* __restrict__ ws)
{
    const int blk = blockIdx.x;
    const int tid = threadIdx.x;
    const int wv  = __builtin_amdgcn_readfirstlane(tid >> 6);
    const int b = blk >> 4, sc = blk & 15;
    const long s  = (long)sc * 256 + tid;
    const float* row = out + O5 + ((long)b * SS + s) * KK;
    float v[KK];
    const float4* r4 = reinterpret_cast<const float4*>(row);
#pragma unroll
    for (int q = 0; q < 8; ++q) {
        const float4 t = r4[q];
        v[4*q] = t.x; v[4*q+1] = t.y; v[4*q+2] = t.z; v[4*q+3] = t.w;
    }
    float m[KK];
#pragma unroll
    for (int k = 0; k < KK; ++k) m[k] = v[k];
    for (int off = 1; off < 64; off <<= 1) {
#pragma unroll
        for (int k = 0; k < KK; ++k) m[k] = fmaxf(m[k], __shfl_xor(m[k], off));
    }
    __shared__ float lm[4][KK];
    __shared__ float lsum[4][KK];
    if ((tid & 63) == 0) {
#pragma unroll
        for (int k = 0; k < KK; ++k) lm[wv][k] = m[k];
    }
    __syncthreads();
#pragma unroll
    for (int k = 0; k < KK; ++k)
        m[k] = fmaxf(fmaxf(lm[0][k], lm[1][k]), fmaxf(lm[2][k], lm[3][k]));
    float sv[KK];
#pragma unroll
    for (int k = 0; k < KK; ++k) sv[k] = __expf(v[k] - m[k]);
    for (int off = 1; off < 64; off <<= 1) {
#pragma unroll
        for (int k = 0; k < KK; ++k) sv[k] += __shfl_xor(sv[k], off);
    }
    if ((tid & 63) == 0) {
#pragma unroll
        for (int k = 0; k < KK; ++k) lsum[wv][k] = sv[k];
    }
    __syncthreads();
    if (tid == 0) {
#pragma unroll
        for (int k = 0; k < KK; ++k) {
            ws[WA + (long)blk * 64 + k]      = m[k];
            ws[WA + (long)blk * 64 + 32 + k] = lsum[0][k] + lsum[1][k] + lsum[2][k] + lsum[3][k];
        }
    }
}

__global__ __launch_bounds__(256) void k_smcomb(float* __restrict__ ws)
{
    const int tid = threadIdx.x;
    const int b = tid >> 5, k = tid & 31;
    float m = -1e30f, s = 0.f;
    for (int c = 0; c < 16; ++c) {
        const float mc = ws[WA + (long)(b * 16 + c) * 64 + k];
        const float sc = ws[WA + (long)(b * 16 + c) * 64 + 32 + k];
        const float nm = fmaxf(m, mc);
        s = s * __expf(m - nm) + sc * __expf(mc - nm);
        m = nm;
    }
    ws[WB + (long)b * 64 + k]      = m;
    ws[WB + (long)b * 64 + 32 + k] = 1.f / s;
}

__global__ __launch_bounds__(256) void k_pw(float* __restrict__ out,
                                            const float* __restrict__ ws)
{
    const long i4 = (long)blockIdx.x * 256 + threadIdx.x;
    const float4 l4 = reinterpret_cast<const float4*>(out + O5)[i4];
    const long idx = i4 * 4;
    const int b  = (int)(idx >> 17);
    const int k0 = (int)(idx & 31);
    const float* mb = ws + WB + (long)b * 64;
    const float lv[4] = {l4.x, l4.y, l4.z, l4.w};
    float r[4];
#pragma unroll
    for (int j = 0; j < 4; ++j) {
        const int k = k0 + j;
        r[j] = __expf(lv[j] - mb[k]) * mb[32 + k];
    }
    reinterpret_cast<float4*>(out + O2)[i4] = make_float4(r[0], r[1], r[2], r[3]);
}

// ============ K3 (k_slots2, proven): pw staged in LDS ======================
__global__ __launch_bounds__(256) void k_slots2(const float* __restrict__ x,
    const float* __restrict__ out, float* __restrict__ dst, int SC, int SLEN)
{
    __shared__ float pwl[2][64 * KK];
    const int tid = threadIdx.x;
    const int blk = blockIdx.x;
    const int sc  = blk % SC;
    const int t2  = blk / SC;
    const int dc  = t2 & 3;
    const int b   = t2 >> 2;
    const int d   = dc * 256 + tid;
    float acc[KK];
#pragma unroll
    for (int k = 0; k < KK; ++k) acc[k] = 0.f;
    const long s0 = (long)sc * SLEN;
    const float* pw = out + O2 + ((long)b * SS + s0) * KK;
    const float* xp = x + ((long)b * SS + s0) * DD + d;
    const int NCH = SLEN >> 6;

    float4 r0 = *reinterpret_cast<const float4*>(pw + tid * 8);
    float4 r1 = *reinterpret_cast<const float4*>(pw + tid * 8 + 4);
    *reinterpret_cast<float4*>(&pwl[0][tid * 8])     = r0;
    *reinterpret_cast<float4*>(&pwl[0][tid * 8 + 4]) = r1;
    __syncthreads();

    for (int ch = 0; ch < NCH; ++ch) {
        const int cb = ch & 1;
        if (ch + 1 < NCH) {
            const float* pn = pw + (long)(ch + 1) * 64 * KK;
            r0 = *reinterpret_cast<const float4*>(pn + tid * 8);
            r1 = *reinterpret_cast<const float4*>(pn + tid * 8 + 4);
        }
        const float* xc = xp + (long)ch * 64 * DD;
        const float* pb = &pwl[cb][0];
#pragma unroll 8
        for (int i = 0; i < 64; ++i) {
            const float xv = xc[(long)i * DD];
#pragma unroll
            for (int q = 0; q < 8; ++q) {
                const float4 w = *reinterpret_cast<const float4*>(pb + i * KK + q * 4);
                acc[4*q]   = fmaf(w.x, xv, acc[4*q]);
                acc[4*q+1] = fmaf(w.y, xv, acc[4*q+1]);
                acc[4*q+2] = fmaf(w.z, xv, acc[4*q+2]);
                acc[4*q+3] = fmaf(w.w, xv, acc[4*q+3]);
            }
        }
        if (ch + 1 < NCH) {
            *reinterpret_cast<float4*>(&pwl[cb ^ 1][tid * 8])     = r0;
            *reinterpret_cast<float4*>(&pwl[cb ^ 1][tid * 8 + 4]) = r1;
        }
        __syncthreads();
    }
    float* o = dst + ((long)(sc * BB + b) * KK) * DD + d;
#pragma unroll
    for (int k = 0; k < KK; ++k) o[(long)k * DD] = acc[k];
}

// ============ K4: reduce SC partials -> soft_slots + expert_inputs =========
__global__ __launch_bounds__(256) void k_red(const float* __restrict__ src,
                                             float* __restrict__ out, int SC)
{
    const long i4 = (long)blockIdx.x * 256 + threadIdx.x;
    float4 s = make_float4(0.f, 0.f, 0.f, 0.f);
    const float4* p = reinterpret_cast<const float4*>(src);
    for (int c = 0; c < SC; ++c) {
        const float4 t = p[(long)c * 65536 + i4];
        s.x += t.x; s.y += t.y; s.z += t.z; s.w += t.w;
    }
    reinterpret_cast<float4*>(out + O3)[i4] = s;
    reinterpret_cast<float4*>(out + O4)[i4] = s;
}

extern "C" void kernel_launch(void* const* d_in, const int* in_sizes, int n_in,
                              void* d_out, int out_size, void* d_ws, size_t ws_size,
                              hipStream_t stream)
{
    const float* x  = (const float*)d_in[0];
    const float* Wp = (const float*)d_in[1];
    const float* bp = (const float*)d_in[2];
    float* out = (float*)d_out;
    float* ws  = (float*)d_ws;

    const size_t wfloats = ws_size / 4;

    if (wfloats >= (size_t)WEND) {
        unsigned short* wh = (unsigned short*)(ws + WPKH);
        unsigned short* wl = (unsigned short*)(ws + WPKL);
        hipLaunchKernelGGL(k_wprep,       dim3(16),   dim3(256), 0, stream, Wp, wh, wl);
        hipLaunchKernelGGL(k_logits_mfma, dim3(1024), dim3(256), 0, stream, x, wh, wl, ws + WC);
        hipLaunchKernelGGL(k_comb2,       dim3(128),  dim3(256), 0, stream, ws + WC, bp, out, ws);
    } else {
        hipLaunchKernelGGL(k_logits4, dim3(512), dim3(256), 0, stream, x, Wp, bp, out);
        hipLaunchKernelGGL(k_smpart,  dim3(128), dim3(256), 0, stream, out, ws);
    }

    hipLaunchKernelGGL(k_smcomb, dim3(1),    dim3(256), 0, stream, ws);
    hipLaunchKernelGGL(k_pw,     dim3(1024), dim3(256), 0, stream, out, ws);

    int SC = 0;
    if      (wfloats >= (size_t)(WC + 32L * 262144)) SC = 32;
    else if (wfloats >= (size_t)(WC + 16L * 262144)) SC = 16;
    else if (wfloats >= (size_t)(WC +  8L * 262144)) SC = 8;
    else if (wfloats >= (size_t)(WC +  4L * 262144)) SC = 4;
    else if (wfloats >= (size_t)(WC +  2L * 262144)) SC = 2;
    else if (wfloats >= (size_t)(WC +  1L * 262144)) SC = 1;

    if (SC >= 1) {
        hipLaunchKernelGGL(k_slots2, dim3(BB * 4 * SC), dim3(256), 0, stream,
                           x, out, ws + WC, SC, SS / SC);
        hipLaunchKernelGGL(k_red,    dim3(256), dim3(256), 0, stream, ws + WC, out, SC);
    } else {
        hipLaunchKernelGGL(k_slots2, dim3(BB * 4), dim3(256), 0, stream,
                           x, out, out + O3, 1, SS);
        hipLaunchKernelGGL(k_red,    dim3(256), dim3(256), 0, stream, out + O3, out, 1);
    }
}